// Round 14
// baseline (400.146 us; speedup 1.0000x reference)
//
#include <hip/hip_runtime.h>
#include <stdint.h>

#define N_NODES 100000
#define N_EDGES 3200000
#define IN_DIM 128
#define HID 64
#define N_GRAPHS 64
#define BN_EPS 1e-5f
#define NSHARD 16
#define BUCK_SH 7
#define BUCK_SZ 128
#define NBUCK ((N_NODES + BUCK_SZ - 1) / BUCK_SZ)   // 782
#define NCNT (NBUCK * 8)                             // 6256
#define BINB_EDGES 4096                              // edges per binning block
#define BIN_BLOCKS ((N_EDGES + BINB_EDGES - 1) / BINB_EDGES)  // 782
#define SLOT_CAP 768                                 // per-(bucket,stream) ebuf slot (mean 512, +11 sigma)
#define BCAP 4608                                    // per-bucket ebuf2 region (mean 4092, +8 sigma)
#define SORT_CAP (8 * SLOT_CAP)                      // 6144, always fits staged bucket
#define AGG_CAP 2048                                 // agg block edge stage (mean 1024)

// __builtin_nontemporal_load needs native (ext_vector) types, not HIP structs.
typedef float vf4 __attribute__((ext_vector_type(4)));
typedef int   vi4 __attribute__((ext_vector_type(4)));
typedef unsigned vu2 __attribute__((ext_vector_type(2)));
typedef _Float16 vh4 __attribute__((ext_vector_type(4)));

__device__ __forceinline__ float4 nt_f4(const float* p) {
    vf4 v = __builtin_nontemporal_load((const vf4*)p);
    return make_float4(v.x, v.y, v.z, v.w);
}
__device__ __forceinline__ int4 nt_i4(const int* p) {
    vi4 v = __builtin_nontemporal_load((const vi4*)p);
    return make_int4(v.x, v.y, v.z, v.w);
}
__device__ __forceinline__ uint2 nt_u2(const uint2* p) {
    vu2 v = __builtin_nontemporal_load((const vu2*)p);
    return make_uint2(v.x, v.y);
}
__device__ __forceinline__ vh4 nt_h4(const _Float16* p) {
    return __builtin_nontemporal_load((const vh4*)p);
}

// ---------------------------------------------------------------------------
// init per-(bucket,stream) cursors to fixed slot bases (replaces count+scan)
__global__ void k_init(int* __restrict__ cur) {
    int i = blockIdx.x * blockDim.x + threadIdx.x;
    if (i < NCNT) cur[i] = i * SLOT_CAP;
}

// bin v3: two passes over GLOBAL (NT streams), LDS = 782-int histogram only
// (3.1 KB -> 8 blocks/CU; round-13's 44.5 KB staging capped at 3 blocks/CU
// with 707K bank conflicts). Pass A: histogram. Reserve: one global atomic
// per non-empty (bucket, s=b&7, XCD-local slot cursor). Pass B: re-read,
// scatter from registers via LDS cursor.
__global__ __launch_bounds__(256) void k_bin(const int* __restrict__ ei,
                                             const float* __restrict__ ew,
                                             int* __restrict__ cur,
                                             uint2* __restrict__ ebuf) {
    __shared__ int hist[NBUCK];
    int b = blockIdx.x, t = threadIdx.x;
    int s = b & 7;
    int base = b * BINB_EDGES;
    int n = min(BINB_EDGES, N_EDGES - base);
    for (int i = t; i < NBUCK; i += 256) hist[i] = 0;
    __syncthreads();
    // pass A: histogram of bucket ids
#pragma unroll
    for (int k = 0; k < 4; ++k) {
        int ch = t + 256 * k;
        if (4 * ch < n) {
            int4 c4 = nt_i4(ei + N_EDGES + base + 4 * ch);
            atomicAdd(&hist[c4.x >> BUCK_SH], 1);
            atomicAdd(&hist[c4.y >> BUCK_SH], 1);
            atomicAdd(&hist[c4.z >> BUCK_SH], 1);
            atomicAdd(&hist[c4.w >> BUCK_SH], 1);
        }
    }
    __syncthreads();
    // reserve: hist[j] becomes the block's running cursor into slot (j, s)
    for (int j = t; j < NBUCK; j += 256) {
        int h = hist[j];
        if (h > 0) hist[j] = atomicAdd(&cur[(j << 3) + s], h);
    }
    __syncthreads();
    // pass B: re-read (NT, L2-cheap) and scatter from registers
#pragma unroll
    for (int k = 0; k < 4; ++k) {
        int ch = t + 256 * k;
        if (4 * ch < n) {
            int4 r4 = nt_i4(ei + base + 4 * ch);
            int4 c4 = nt_i4(ei + N_EDGES + base + 4 * ch);
            float4 w4 = nt_f4(ew + base + 4 * ch);
            int rr[4] = {r4.x, r4.y, r4.z, r4.w};
            int cc[4] = {c4.x, c4.y, c4.z, c4.w};
            float ww[4] = {w4.x, w4.y, w4.z, w4.w};
#pragma unroll
            for (int u = 0; u < 4; ++u) {
                int bk = cc[u] >> BUCK_SH;
                int pos = atomicAdd(&hist[bk], 1);
                ebuf[pos] = make_uint2(
                    (unsigned)(rr[u] | ((cc[u] & (BUCK_SZ - 1)) << 17)),
                    __float_as_uint(ww[u]));
            }
        }
    }
}

// ---------------------------------------------------------------------------
// fused prep (dinv-factorized, slotted input): per bucket, read the 8 slots
// (lengths from cursors), stage in LDS, compute weighted degree -> dinv[c]
// (bucket-LOCAL, no cross-block race), dest histogram -> per-node ranges,
// scatter compacted into ebuf2[b*BCAP ...] with w' = w * dinv[c].
__global__ __launch_bounds__(256) void k_sortnorm(const uint2* __restrict__ ebuf,
                                                  const int* __restrict__ cur,
                                                  float* __restrict__ dinv,
                                                  uint2* __restrict__ ebuf2,
                                                  int2* __restrict__ nrange) {
    __shared__ uint2 se[SORT_CAP];
    __shared__ float sdi[BUCK_SZ];   // degree accum, then dinv
    __shared__ int scnt[BUCK_SZ];
    __shared__ int scur[BUCK_SZ];
    __shared__ int slen[8], soffc[8];
    int b = blockIdx.x, t = threadIdx.x;
    if (t < BUCK_SZ) { sdi[t] = 0.f; scnt[t] = 0; }
    if (t < 8) slen[t] = cur[(b << 3) + t] - ((b << 3) + t) * SLOT_CAP;
    __syncthreads();
    if (t == 0) {
        int run = 0;
#pragma unroll
        for (int s = 0; s < 8; ++s) { soffc[s] = run; run += slen[s]; }
    }
    __syncthreads();
    // pass 1: stage all 8 segments compactly + weighted degree + histogram
    for (int s = 0; s < 8; ++s) {
        int sb = ((b << 3) + s) * SLOT_CAP;
        int len = slen[s];
        int off = soffc[s];
        for (int i = t; i < len; i += 256) {
            uint2 u = nt_u2(ebuf + sb + i);
            se[off + i] = u;
            int cl = u.x >> 17;
            atomicAdd(&sdi[cl], __uint_as_float(u.y));
            atomicAdd(&scnt[cl], 1);
        }
    }
    __syncthreads();
    int n = soffc[7] + slen[7];
    if (t < BUCK_SZ) {
        float di = rsqrtf(sdi[t] + 1.0f);   // +1 = self-loop weight
        int node = b * BUCK_SZ + t;
        if (node < N_NODES) dinv[node] = di;
        sdi[t] = di;
    }
    __syncthreads();
    // inclusive scan over 128 counts (all 256 threads hit barriers)
    for (int off = 1; off < BUCK_SZ; off <<= 1) {
        int x = 0;
        if (t < BUCK_SZ && t >= off) x = scnt[t - off];
        __syncthreads();
        if (t < BUCK_SZ) scnt[t] += x;
        __syncthreads();
    }
    if (t < BUCK_SZ) {
        int excl = (t > 0) ? scnt[t - 1] : 0;
        int cnt = scnt[t] - excl;
        scur[t] = b * BCAP + excl;
        int node = b * BUCK_SZ + t;
        if (node < N_NODES) nrange[node] = make_int2(b * BCAP + excl, b * BCAP + excl + cnt);
    }
    __syncthreads();
    // pass 2: scatter within bucket + w' = w * dinv[c]
    for (int i = t; i < n; i += 256) {
        uint2 u = se[i];
        int r = u.x & 131071;
        int cl = u.x >> 17;
        float nm = __uint_as_float(u.y) * sdi[cl];
        int p = atomicAdd(&scur[cl], 1);
        ebuf2[p] = make_uint2((unsigned)r, __float_as_uint(nm));
    }
}

// ---------------------------------------------------------------------------
// GEMM: out[n][c] = dinv[n] * sum_k in[n][k]*W[k][c]; fp16 output (h' = dinv*h).
// BNH: input is fp16 with fused BN+ReLU (layer 2); else f32 input (layer 1).
template <int K, bool BNH>
__global__ __launch_bounds__(256) void k_gemm(const void* __restrict__ in_,
                                              const float* __restrict__ W,
                                              const float* __restrict__ scale,
                                              const float* __restrict__ shift,
                                              const float* __restrict__ dinv,
                                              _Float16* __restrict__ out) {
    __shared__ float ws[K * 64];
    __shared__ float xs[32 * 132];
    __shared__ float ssc[64], ssh[64];
    int t = threadIdx.x;
    int nbase = blockIdx.x * 128;

#pragma unroll
    for (int i = 0; i < K / 16; ++i) {
        int idx = t + 256 * i;
        ((float4*)ws)[idx] = ((const float4*)W)[idx];
    }
    if (BNH && t < 64) { ssc[t] = scale[t]; ssh[t] = shift[t]; }

    int cg = t & 15;
    int ng = t >> 4;
    float acc[8][4];
#pragma unroll
    for (int i = 0; i < 8; ++i)
#pragma unroll
        for (int j = 0; j < 4; ++j) acc[i][j] = 0.f;

    for (int k0 = 0; k0 < K; k0 += 32) {
        __syncthreads();
#pragma unroll
        for (int i = 0; i < 4; ++i) {
            int idx = t + 256 * i;
            int row = idx >> 3;
            int kq = idx & 7;
            int node = nbase + row;
            float vv[4] = {0.f, 0.f, 0.f, 0.f};
            if (node < N_NODES) {
                if (BNH) {
                    vh4 v = nt_h4((const _Float16*)in_ + (size_t)node * K + k0 + kq * 4);
                    vv[0] = (float)v.x; vv[1] = (float)v.y;
                    vv[2] = (float)v.z; vv[3] = (float)v.w;
                } else {
                    float4 v = nt_f4((const float*)in_ + (size_t)node * K + k0 + kq * 4);
                    vv[0] = v.x; vv[1] = v.y; vv[2] = v.z; vv[3] = v.w;
                }
            }
#pragma unroll
            for (int u = 0; u < 4; ++u) {
                float val = vv[u];
                if (BNH) {
                    int k = k0 + kq * 4 + u;
                    val = fmaxf(ssc[k] * val + ssh[k], 0.f);
                }
                xs[(kq * 4 + u) * 132 + row] = val;
            }
        }
        __syncthreads();
#pragma unroll
        for (int k = 0; k < 32; ++k) {
            float4 wv = *(const float4*)(ws + (k0 + k) * 64 + cg * 4);
            float4 xa = *(const float4*)(xs + k * 132 + ng * 8);
            float4 xb = *(const float4*)(xs + k * 132 + ng * 8 + 4);
            float xv[8] = {xa.x, xa.y, xa.z, xa.w, xb.x, xb.y, xb.z, xb.w};
            float wvv[4] = {wv.x, wv.y, wv.z, wv.w};
#pragma unroll
            for (int i = 0; i < 8; ++i)
#pragma unroll
                for (int j = 0; j < 4; ++j) acc[i][j] += xv[i] * wvv[j];
        }
    }
#pragma unroll
    for (int i = 0; i < 8; ++i) {
        int node = nbase + ng * 8 + i;
        if (node < N_NODES) {
            float dv = dinv[node];
            vh4 o;
            o.x = (_Float16)(acc[i][0] * dv); o.y = (_Float16)(acc[i][1] * dv);
            o.z = (_Float16)(acc[i][2] * dv); o.w = (_Float16)(acc[i][3] * dv);
            *(vh4*)(out + (size_t)node * 64 + cg * 4) = o;
        }
    }
}

// ---------------------------------------------------------------------------
// CSR gather-aggregation: block stages its 32 nodes' contiguous edge metas in
// LDS; per-edge path is ds_read -> independent row gather, 16-deep pipelined.
//   out[v] = sum w'*h'[r] + dinv[v]*h'[v] + bias   (== GCN layer exactly)
__global__ __launch_bounds__(256) void k_agg(const _Float16* __restrict__ hin,
                                             const uint2* __restrict__ ebuf2,
                                             const int2* __restrict__ nrange,
                                             const float* __restrict__ dinv,
                                             const float* __restrict__ bias,
                                             _Float16* __restrict__ hout,
                                             float* __restrict__ bn_shard) {
    __shared__ uint2 sme[AGG_CAP];
    __shared__ float sm[4][64], qm[4][64];
    int b = blockIdx.x, t = threadIdx.x;
    int wave = t >> 6, lane = t & 63;
    int vbase0 = b * 32;                       // grid is exactly N_NODES/32
    int ebeg = nrange[vbase0].x;
    int eend = nrange[vbase0 + 31].y;
    int n = eend - ebeg;
    bool fit = (n <= AGG_CAP);
    if (fit) {
        for (int i = t; i < n; i += 256) sme[i] = nt_u2(ebuf2 + ebeg + i);
    }
    __syncthreads();

    float s = 0.f, q = 0.f;
    float bl = bias[lane];
    int vbase = vbase0 + wave * 8;
    for (int vi = 0; vi < 8; ++vi) {
        int v = vbase + vi;
        int2 be = nrange[v];
        int beg = be.x, end = be.y;
        float acc = 0.f;
        int j = beg;
        if (fit) {
            for (; j + 16 <= end; j += 16) {
                float fv[16], fn[16];
#pragma unroll
                for (int u = 0; u < 16; ++u) {
                    uint2 e = sme[j - ebeg + u];
                    fn[u] = __uint_as_float(e.y);
                    fv[u] = (float)hin[((size_t)e.x << 6) + lane];
                }
#pragma unroll
                for (int u = 0; u < 16; ++u) acc = fmaf(fn[u], fv[u], acc);
            }
            for (; j + 8 <= end; j += 8) {
                float fv[8], fn[8];
#pragma unroll
                for (int u = 0; u < 8; ++u) {
                    uint2 e = sme[j - ebeg + u];
                    fn[u] = __uint_as_float(e.y);
                    fv[u] = (float)hin[((size_t)e.x << 6) + lane];
                }
#pragma unroll
                for (int u = 0; u < 8; ++u) acc = fmaf(fn[u], fv[u], acc);
            }
            for (; j < end; ++j) {
                uint2 e = sme[j - ebeg];
                acc = fmaf(__uint_as_float(e.y),
                           (float)hin[((size_t)e.x << 6) + lane], acc);
            }
        } else {
            for (; j + 8 <= end; j += 8) {
                float fv[8], fn[8];
#pragma unroll
                for (int u = 0; u < 8; ++u) {
                    uint2 e = nt_u2(ebuf2 + j + u);
                    fn[u] = __uint_as_float(e.y);
                    fv[u] = (float)hin[((size_t)e.x << 6) + lane];
                }
#pragma unroll
                for (int u = 0; u < 8; ++u) acc = fmaf(fn[u], fv[u], acc);
            }
            for (; j < end; ++j) {
                uint2 e = nt_u2(ebuf2 + j);
                acc = fmaf(__uint_as_float(e.y),
                           (float)hin[((size_t)e.x << 6) + lane], acc);
            }
        }
        float dv = dinv[v];
        acc = fmaf(dv, (float)hin[((size_t)v << 6) + lane], acc);  // dinv*h' = dinv^2*h
        acc += bl;
        hout[((size_t)v << 6) + lane] = (_Float16)acc;
        s += acc;
        q += acc * acc;
    }
    sm[wave][lane] = s;
    qm[wave][lane] = q;
    __syncthreads();
    if (wave == 0) {
        float ts = sm[0][lane] + sm[1][lane] + sm[2][lane] + sm[3][lane];
        float tq = qm[0][lane] + qm[1][lane] + qm[2][lane] + qm[3][lane];
        float* shard = bn_shard + (blockIdx.x & (NSHARD - 1)) * 128;
        atomicAdd(&shard[lane], ts);
        atomicAdd(&shard[64 + lane], tq);
    }
}

// reduce BN shards -> scale/shift; re-zero shards for the next layer
__global__ void k_bn_final(float* __restrict__ bn_shard, const float* __restrict__ gamma,
                           const float* __restrict__ beta, float* __restrict__ scale,
                           float* __restrict__ shift) {
    int t = threadIdx.x;
    if (t < 64) {
        float s = 0.f, q = 0.f;
        for (int i = 0; i < NSHARD; ++i) {
            s += bn_shard[i * 128 + t];
            q += bn_shard[i * 128 + 64 + t];
        }
        float mean = s * (1.0f / N_NODES);
        float var = q * (1.0f / N_NODES) - mean * mean;
        float sc = gamma[t] * rsqrtf(var + BN_EPS);
        scale[t] = sc;
        shift[t] = beta[t] - mean * sc;
    }
    __syncthreads();
    for (int i = t; i < NSHARD * 128; i += 256) bn_shard[i] = 0.f;
}

// ---------------------------------------------------------------------------
// pool: 782 blocks x 128 rows, sharded accumulators (blockIdx&15, XCD-local)
__global__ __launch_bounds__(256) void k_pool(const _Float16* __restrict__ a2,
                                              const float* __restrict__ scale,
                                              const float* __restrict__ shift,
                                              const int* __restrict__ batch,
                                              float* __restrict__ pooled_sh,
                                              float* __restrict__ pcnt_sh) {
    int b = blockIdx.x, t = threadIdx.x;
    int c = t & 63;
    int rg = t >> 6;
    int base = b * BUCK_SZ;
    float sc = scale[c], sh = shift[c];
    float* pool_s = pooled_sh + (size_t)(b & (NSHARD - 1)) * (N_GRAPHS * 64);
    float* pcnt_s = pcnt_sh + (size_t)(b & (NSHARD - 1)) * N_GRAPHS;
    int gcur = -1;
    float acc = 0.f, cacc = 0.f;
    for (int i = rg; i < BUCK_SZ; i += 4) {
        int v = base + i;
        if (v >= N_NODES) break;
        int g = batch[v];
        if (g != gcur) {
            if (gcur >= 0) {
                atomicAdd(&pool_s[gcur * 64 + c], acc);
                if (c == 0) atomicAdd(&pcnt_s[gcur], cacc);
            }
            gcur = g;
            acc = 0.f;
            cacc = 0.f;
        }
        float h = fmaxf(sc * (float)a2[(size_t)v * 64 + c] + sh, 0.f);
        acc += h;
        cacc += 1.f;
    }
    if (gcur >= 0) {
        atomicAdd(&pool_s[gcur * 64 + c], acc);
        if (c == 0) atomicAdd(&pcnt_s[gcur], cacc);
    }
}

__global__ void k_out(const float* __restrict__ pooled_sh,
                      const float* __restrict__ pcnt_sh,
                      const float* __restrict__ Wout, const float* __restrict__ bout,
                      float* __restrict__ out) {
    int g = threadIdx.x;
    if (g < N_GRAPHS) {
        float cnt = 0.f;
        for (int s = 0; s < NSHARD; ++s) cnt += pcnt_sh[s * N_GRAPHS + g];
        cnt = fmaxf(cnt, 1.0f);
        float sum = 0.f;
        for (int c = 0; c < 64; ++c) {
            float p = 0.f;
            for (int s = 0; s < NSHARD; ++s)
                p += pooled_sh[(size_t)s * N_GRAPHS * 64 + g * 64 + c];
            sum += p * Wout[c];
        }
        out[g] = sum / cnt + bout[0];
    }
}

// ---------------------------------------------------------------------------
extern "C" void kernel_launch(void* const* d_in, const int* in_sizes, int n_in,
                              void* d_out, int out_size, void* d_ws, size_t ws_size,
                              hipStream_t stream) {
    const float* x    = (const float*)d_in[0];
    const int*   ei   = (const int*)d_in[1];
    const float* ew   = (const float*)d_in[2];
    const int*   batch= (const int*)d_in[3];
    const float* W1   = (const float*)d_in[4];
    const float* b1   = (const float*)d_in[5];
    const float* W2   = (const float*)d_in[6];
    const float* b2   = (const float*)d_in[7];
    const float* g1   = (const float*)d_in[8];
    const float* be1  = (const float*)d_in[9];
    const float* g2   = (const float*)d_in[10];
    const float* be2  = (const float*)d_in[11];
    const float* Wout = (const float*)d_in[12];
    const float* bout = (const float*)d_in[13];
    float* out = (float*)d_out;

    char* w = (char*)d_ws;
    size_t o = 0;
    auto alloc = [&](size_t bytes) -> void* {
        void* p = w + o;
        o = (o + bytes + 255) & ~(size_t)255;
        return p;
    };
    int*   cur     = (int*)alloc(NCNT * 4);
    int2*  nrange  = (int2*)alloc((size_t)N_NODES * 8);
    float* dinv    = (float*)alloc(N_NODES * 4);
    float* bnshard = (float*)alloc(NSHARD * 128 * 4);
    float* scale1  = (float*)alloc(64 * 4);
    float* shift1  = (float*)alloc(64 * 4);
    float* scale2  = (float*)alloc(64 * 4);
    float* shift2  = (float*)alloc(64 * 4);
    float* pooled  = (float*)alloc(NSHARD * N_GRAPHS * 64 * 4);
    float* pcnt    = (float*)alloc(NSHARD * N_GRAPHS * 4);
    uint2* ebuf2   = (uint2*)alloc((size_t)NBUCK * BCAP * 8);     // 28.8 MB
    // 38.4 MB region double-use: ebuf (slotted binning scratch, dead after
    // k_sortnorm), then two fp16 node buffers HA/HB (12.8 MB each).
    uint2* ebuf    = (uint2*)alloc((size_t)NCNT * SLOT_CAP * 8);  // 38.4 MB
    _Float16* bufHA = (_Float16*)ebuf;
    _Float16* bufHB = bufHA + (size_t)N_NODES * 64;
    if (o > ws_size) return;

    (void)hipMemsetAsync(bnshard, 0, NSHARD * 128 * 4, stream);
    (void)hipMemsetAsync(pooled, 0, NSHARD * N_GRAPHS * 64 * 4, stream);
    (void)hipMemsetAsync(pcnt, 0, NSHARD * N_GRAPHS * 4, stream);

    k_init<<<(NCNT + 255) / 256, 256, 0, stream>>>(cur);
    k_bin<<<BIN_BLOCKS, 256, 0, stream>>>(ei, ew, cur, ebuf);
    k_sortnorm<<<NBUCK, 256, 0, stream>>>(ebuf, cur, dinv, ebuf2, nrange);

    // layer 1: x (f32) -> h1' = dinv*(x@W1) (fp16) -> a1 (fp16) + BN1 stats
    k_gemm<128, false><<<(N_NODES + 127) / 128, 256, 0, stream>>>(x, W1, nullptr, nullptr, dinv, bufHA);
    k_agg<<<N_NODES / 32, 256, 0, stream>>>(bufHA, ebuf2, nrange, dinv, b1, bufHB, bnshard);
    k_bn_final<<<1, 256, 0, stream>>>(bnshard, g1, be1, scale1, shift1);

    // layer 2: a1 (fp16, fused BN+ReLU) -> h2' (fp16) -> a2 (fp16) + BN2 stats
    k_gemm<64, true><<<(N_NODES + 127) / 128, 256, 0, stream>>>(bufHB, W2, scale1, shift1, dinv, bufHA);
    k_agg<<<N_NODES / 32, 256, 0, stream>>>(bufHA, ebuf2, nrange, dinv, b2, bufHB, bnshard);
    k_bn_final<<<1, 256, 0, stream>>>(bnshard, g2, be2, scale2, shift2);

    // pool (fused BN2+ReLU, sharded accumulators) + output
    k_pool<<<NBUCK, 256, 0, stream>>>(bufHB, scale2, shift2, batch, pooled, pcnt);
    k_out<<<1, 64, 0, stream>>>(pooled, pcnt, Wout, bout, out);
}

// Round 15
// 378.067 us; speedup vs baseline: 1.0584x; 1.0584x over previous
//
#include <hip/hip_runtime.h>
#include <stdint.h>

#define N_NODES 100000
#define N_EDGES 3200000
#define IN_DIM 128
#define HID 64
#define N_GRAPHS 64
#define BN_EPS 1e-5f
#define NSHARD 16
#define BUCK_SH 7
#define BUCK_SZ 128
#define NBUCK ((N_NODES + BUCK_SZ - 1) / BUCK_SZ)   // 782
#define NCNT (NBUCK * 8)                             // 6256
#define BINB_EDGES 4096                              // edges per binning block
#define BIN_BLOCKS ((N_EDGES + BINB_EDGES - 1) / BINB_EDGES)  // 782
#define SLOT_CAP 768                                 // per-(bucket,stream) ebuf slot (mean 512, +11 sigma)
#define BCAP 4608                                    // per-bucket ebuf2 region (mean 4092, +8 sigma)
#define SORT_CAP (8 * SLOT_CAP)                      // 6144, always fits staged bucket
#define AGG_CAP 2048                                 // agg block edge stage (mean 1024)

// __builtin_nontemporal_load needs native (ext_vector) types, not HIP structs.
typedef float vf4 __attribute__((ext_vector_type(4)));
typedef int   vi4 __attribute__((ext_vector_type(4)));
typedef unsigned vu2 __attribute__((ext_vector_type(2)));
typedef _Float16 vh4 __attribute__((ext_vector_type(4)));

__device__ __forceinline__ float4 nt_f4(const float* p) {
    vf4 v = __builtin_nontemporal_load((const vf4*)p);
    return make_float4(v.x, v.y, v.z, v.w);
}
__device__ __forceinline__ int4 nt_i4(const int* p) {
    vi4 v = __builtin_nontemporal_load((const vi4*)p);
    return make_int4(v.x, v.y, v.z, v.w);
}
__device__ __forceinline__ uint2 nt_u2(const uint2* p) {
    vu2 v = __builtin_nontemporal_load((const vu2*)p);
    return make_uint2(v.x, v.y);
}
__device__ __forceinline__ vh4 nt_h4(const _Float16* p) {
    return __builtin_nontemporal_load((const vh4*)p);
}

// ---------------------------------------------------------------------------
// init per-(bucket,stream) cursors to fixed slot bases (replaces count+scan)
__global__ void k_init(int* __restrict__ cur) {
    int i = blockIdx.x * blockDim.x + threadIdx.x;
    if (i < NCNT) cur[i] = i * SLOT_CAP;
}

// bin v4: two NT passes over global, LDS = 782-int histogram only, and
// 512 THREADS (8 waves/block). Grid 782 caps residency at ~3 blocks/CU, so
// 256-thread blocks pinned occupancy at 12/32 waves (rounds 13+14, measured
// 26%); 8 waves/block -> ~24/32 waves. Pass A: histogram. Reserve: one
// global atomic per non-empty (bucket, s=b&7 XCD-local). Pass B: re-read,
// scatter from registers (positions batched before stores).
__global__ __launch_bounds__(512) void k_bin(const int* __restrict__ ei,
                                             const float* __restrict__ ew,
                                             int* __restrict__ cur,
                                             uint2* __restrict__ ebuf) {
    __shared__ int hist[NBUCK];
    int b = blockIdx.x, t = threadIdx.x;
    int s = b & 7;
    int base = b * BINB_EDGES;
    int n = min(BINB_EDGES, N_EDGES - base);
    for (int i = t; i < NBUCK; i += 512) hist[i] = 0;
    __syncthreads();
    // pass A: histogram of bucket ids (8 edges/thread = 2 chunks of 4)
#pragma unroll
    for (int k = 0; k < 2; ++k) {
        int ch = t + 512 * k;
        if (4 * ch < n) {
            int4 c4 = nt_i4(ei + N_EDGES + base + 4 * ch);
            atomicAdd(&hist[c4.x >> BUCK_SH], 1);
            atomicAdd(&hist[c4.y >> BUCK_SH], 1);
            atomicAdd(&hist[c4.z >> BUCK_SH], 1);
            atomicAdd(&hist[c4.w >> BUCK_SH], 1);
        }
    }
    __syncthreads();
    // reserve: hist[j] becomes the block's running cursor into slot (j, s)
    for (int j = t; j < NBUCK; j += 512) {
        int h = hist[j];
        if (h > 0) hist[j] = atomicAdd(&cur[(j << 3) + s], h);
    }
    __syncthreads();
    // pass B: re-read (NT, L2/L3-cheap) and scatter from registers
#pragma unroll
    for (int k = 0; k < 2; ++k) {
        int ch = t + 512 * k;
        if (4 * ch < n) {
            int4 r4 = nt_i4(ei + base + 4 * ch);
            int4 c4 = nt_i4(ei + N_EDGES + base + 4 * ch);
            float4 w4 = nt_f4(ew + base + 4 * ch);
            int rr[4] = {r4.x, r4.y, r4.z, r4.w};
            int cc[4] = {c4.x, c4.y, c4.z, c4.w};
            float ww[4] = {w4.x, w4.y, w4.z, w4.w};
            int pos[4];
#pragma unroll
            for (int u = 0; u < 4; ++u)
                pos[u] = atomicAdd(&hist[cc[u] >> BUCK_SH], 1);
#pragma unroll
            for (int u = 0; u < 4; ++u)
                ebuf[pos[u]] = make_uint2(
                    (unsigned)(rr[u] | ((cc[u] & (BUCK_SZ - 1)) << 17)),
                    __float_as_uint(ww[u]));
        }
    }
}

// ---------------------------------------------------------------------------
// fused prep (dinv-factorized, slotted input): per bucket, read the 8 slots
// (lengths from cursors), stage in LDS, compute weighted degree -> dinv[c]
// (bucket-LOCAL, no cross-block race), dest histogram -> per-node ranges,
// scatter compacted into ebuf2[b*BCAP ...] with w' = w * dinv[c].
__global__ __launch_bounds__(256) void k_sortnorm(const uint2* __restrict__ ebuf,
                                                  const int* __restrict__ cur,
                                                  float* __restrict__ dinv,
                                                  uint2* __restrict__ ebuf2,
                                                  int2* __restrict__ nrange) {
    __shared__ uint2 se[SORT_CAP];
    __shared__ float sdi[BUCK_SZ];   // degree accum, then dinv
    __shared__ int scnt[BUCK_SZ];
    __shared__ int scur[BUCK_SZ];
    __shared__ int slen[8], soffc[8];
    int b = blockIdx.x, t = threadIdx.x;
    if (t < BUCK_SZ) { sdi[t] = 0.f; scnt[t] = 0; }
    if (t < 8) slen[t] = cur[(b << 3) + t] - ((b << 3) + t) * SLOT_CAP;
    __syncthreads();
    if (t == 0) {
        int run = 0;
#pragma unroll
        for (int s = 0; s < 8; ++s) { soffc[s] = run; run += slen[s]; }
    }
    __syncthreads();
    // pass 1: stage all 8 segments compactly + weighted degree + histogram
    for (int s = 0; s < 8; ++s) {
        int sb = ((b << 3) + s) * SLOT_CAP;
        int len = slen[s];
        int off = soffc[s];
        for (int i = t; i < len; i += 256) {
            uint2 u = nt_u2(ebuf + sb + i);
            se[off + i] = u;
            int cl = u.x >> 17;
            atomicAdd(&sdi[cl], __uint_as_float(u.y));
            atomicAdd(&scnt[cl], 1);
        }
    }
    __syncthreads();
    int n = soffc[7] + slen[7];
    if (t < BUCK_SZ) {
        float di = rsqrtf(sdi[t] + 1.0f);   // +1 = self-loop weight
        int node = b * BUCK_SZ + t;
        if (node < N_NODES) dinv[node] = di;
        sdi[t] = di;
    }
    __syncthreads();
    // inclusive scan over 128 counts (all 256 threads hit barriers)
    for (int off = 1; off < BUCK_SZ; off <<= 1) {
        int x = 0;
        if (t < BUCK_SZ && t >= off) x = scnt[t - off];
        __syncthreads();
        if (t < BUCK_SZ) scnt[t] += x;
        __syncthreads();
    }
    if (t < BUCK_SZ) {
        int excl = (t > 0) ? scnt[t - 1] : 0;
        int cnt = scnt[t] - excl;
        scur[t] = b * BCAP + excl;
        int node = b * BUCK_SZ + t;
        if (node < N_NODES) nrange[node] = make_int2(b * BCAP + excl, b * BCAP + excl + cnt);
    }
    __syncthreads();
    // pass 2: scatter within bucket + w' = w * dinv[c]
    for (int i = t; i < n; i += 256) {
        uint2 u = se[i];
        int r = u.x & 131071;
        int cl = u.x >> 17;
        float nm = __uint_as_float(u.y) * sdi[cl];
        int p = atomicAdd(&scur[cl], 1);
        ebuf2[p] = make_uint2((unsigned)r, __float_as_uint(nm));
    }
}

// ---------------------------------------------------------------------------
// GEMM: out[n][c] = dinv[n] * sum_k in[n][k]*W[k][c]; fp16 output (h' = dinv*h).
// BNH: input is fp16 with fused BN+ReLU (layer 2); else f32 input (layer 1).
template <int K, bool BNH>
__global__ __launch_bounds__(256) void k_gemm(const void* __restrict__ in_,
                                              const float* __restrict__ W,
                                              const float* __restrict__ scale,
                                              const float* __restrict__ shift,
                                              const float* __restrict__ dinv,
                                              _Float16* __restrict__ out) {
    __shared__ float ws[K * 64];
    __shared__ float xs[32 * 132];
    __shared__ float ssc[64], ssh[64];
    int t = threadIdx.x;
    int nbase = blockIdx.x * 128;

#pragma unroll
    for (int i = 0; i < K / 16; ++i) {
        int idx = t + 256 * i;
        ((float4*)ws)[idx] = ((const float4*)W)[idx];
    }
    if (BNH && t < 64) { ssc[t] = scale[t]; ssh[t] = shift[t]; }

    int cg = t & 15;
    int ng = t >> 4;
    float acc[8][4];
#pragma unroll
    for (int i = 0; i < 8; ++i)
#pragma unroll
        for (int j = 0; j < 4; ++j) acc[i][j] = 0.f;

    for (int k0 = 0; k0 < K; k0 += 32) {
        __syncthreads();
#pragma unroll
        for (int i = 0; i < 4; ++i) {
            int idx = t + 256 * i;
            int row = idx >> 3;
            int kq = idx & 7;
            int node = nbase + row;
            float vv[4] = {0.f, 0.f, 0.f, 0.f};
            if (node < N_NODES) {
                if (BNH) {
                    vh4 v = nt_h4((const _Float16*)in_ + (size_t)node * K + k0 + kq * 4);
                    vv[0] = (float)v.x; vv[1] = (float)v.y;
                    vv[2] = (float)v.z; vv[3] = (float)v.w;
                } else {
                    float4 v = nt_f4((const float*)in_ + (size_t)node * K + k0 + kq * 4);
                    vv[0] = v.x; vv[1] = v.y; vv[2] = v.z; vv[3] = v.w;
                }
            }
#pragma unroll
            for (int u = 0; u < 4; ++u) {
                float val = vv[u];
                if (BNH) {
                    int k = k0 + kq * 4 + u;
                    val = fmaxf(ssc[k] * val + ssh[k], 0.f);
                }
                xs[(kq * 4 + u) * 132 + row] = val;
            }
        }
        __syncthreads();
#pragma unroll
        for (int k = 0; k < 32; ++k) {
            float4 wv = *(const float4*)(ws + (k0 + k) * 64 + cg * 4);
            float4 xa = *(const float4*)(xs + k * 132 + ng * 8);
            float4 xb = *(const float4*)(xs + k * 132 + ng * 8 + 4);
            float xv[8] = {xa.x, xa.y, xa.z, xa.w, xb.x, xb.y, xb.z, xb.w};
            float wvv[4] = {wv.x, wv.y, wv.z, wv.w};
#pragma unroll
            for (int i = 0; i < 8; ++i)
#pragma unroll
                for (int j = 0; j < 4; ++j) acc[i][j] += xv[i] * wvv[j];
        }
    }
#pragma unroll
    for (int i = 0; i < 8; ++i) {
        int node = nbase + ng * 8 + i;
        if (node < N_NODES) {
            float dv = dinv[node];
            vh4 o;
            o.x = (_Float16)(acc[i][0] * dv); o.y = (_Float16)(acc[i][1] * dv);
            o.z = (_Float16)(acc[i][2] * dv); o.w = (_Float16)(acc[i][3] * dv);
            *(vh4*)(out + (size_t)node * 64 + cg * 4) = o;
        }
    }
}

// ---------------------------------------------------------------------------
// CSR gather-aggregation: block stages its 32 nodes' contiguous edge metas in
// LDS; per-edge path is ds_read -> independent row gather, 16-deep pipelined.
//   out[v] = sum w'*h'[r] + dinv[v]*h'[v] + bias   (== GCN layer exactly)
__global__ __launch_bounds__(256) void k_agg(const _Float16* __restrict__ hin,
                                             const uint2* __restrict__ ebuf2,
                                             const int2* __restrict__ nrange,
                                             const float* __restrict__ dinv,
                                             const float* __restrict__ bias,
                                             _Float16* __restrict__ hout,
                                             float* __restrict__ bn_shard) {
    __shared__ uint2 sme[AGG_CAP];
    __shared__ float sm[4][64], qm[4][64];
    int b = blockIdx.x, t = threadIdx.x;
    int wave = t >> 6, lane = t & 63;
    int vbase0 = b * 32;                       // grid is exactly N_NODES/32
    int ebeg = nrange[vbase0].x;
    int eend = nrange[vbase0 + 31].y;
    int n = eend - ebeg;
    bool fit = (n <= AGG_CAP);
    if (fit) {
        for (int i = t; i < n; i += 256) sme[i] = nt_u2(ebuf2 + ebeg + i);
    }
    __syncthreads();

    float s = 0.f, q = 0.f;
    float bl = bias[lane];
    int vbase = vbase0 + wave * 8;
    for (int vi = 0; vi < 8; ++vi) {
        int v = vbase + vi;
        int2 be = nrange[v];
        int beg = be.x, end = be.y;
        float acc = 0.f;
        int j = beg;
        if (fit) {
            for (; j + 16 <= end; j += 16) {
                float fv[16], fn[16];
#pragma unroll
                for (int u = 0; u < 16; ++u) {
                    uint2 e = sme[j - ebeg + u];
                    fn[u] = __uint_as_float(e.y);
                    fv[u] = (float)hin[((size_t)e.x << 6) + lane];
                }
#pragma unroll
                for (int u = 0; u < 16; ++u) acc = fmaf(fn[u], fv[u], acc);
            }
            for (; j + 8 <= end; j += 8) {
                float fv[8], fn[8];
#pragma unroll
                for (int u = 0; u < 8; ++u) {
                    uint2 e = sme[j - ebeg + u];
                    fn[u] = __uint_as_float(e.y);
                    fv[u] = (float)hin[((size_t)e.x << 6) + lane];
                }
#pragma unroll
                for (int u = 0; u < 8; ++u) acc = fmaf(fn[u], fv[u], acc);
            }
            for (; j < end; ++j) {
                uint2 e = sme[j - ebeg];
                acc = fmaf(__uint_as_float(e.y),
                           (float)hin[((size_t)e.x << 6) + lane], acc);
            }
        } else {
            for (; j + 8 <= end; j += 8) {
                float fv[8], fn[8];
#pragma unroll
                for (int u = 0; u < 8; ++u) {
                    uint2 e = nt_u2(ebuf2 + j + u);
                    fn[u] = __uint_as_float(e.y);
                    fv[u] = (float)hin[((size_t)e.x << 6) + lane];
                }
#pragma unroll
                for (int u = 0; u < 8; ++u) acc = fmaf(fn[u], fv[u], acc);
            }
            for (; j < end; ++j) {
                uint2 e = nt_u2(ebuf2 + j);
                acc = fmaf(__uint_as_float(e.y),
                           (float)hin[((size_t)e.x << 6) + lane], acc);
            }
        }
        float dv = dinv[v];
        acc = fmaf(dv, (float)hin[((size_t)v << 6) + lane], acc);  // dinv*h' = dinv^2*h
        acc += bl;
        hout[((size_t)v << 6) + lane] = (_Float16)acc;
        s += acc;
        q += acc * acc;
    }
    sm[wave][lane] = s;
    qm[wave][lane] = q;
    __syncthreads();
    if (wave == 0) {
        float ts = sm[0][lane] + sm[1][lane] + sm[2][lane] + sm[3][lane];
        float tq = qm[0][lane] + qm[1][lane] + qm[2][lane] + qm[3][lane];
        float* shard = bn_shard + (blockIdx.x & (NSHARD - 1)) * 128;
        atomicAdd(&shard[lane], ts);
        atomicAdd(&shard[64 + lane], tq);
    }
}

// reduce BN shards -> scale/shift; re-zero shards for the next layer
__global__ void k_bn_final(float* __restrict__ bn_shard, const float* __restrict__ gamma,
                           const float* __restrict__ beta, float* __restrict__ scale,
                           float* __restrict__ shift) {
    int t = threadIdx.x;
    if (t < 64) {
        float s = 0.f, q = 0.f;
        for (int i = 0; i < NSHARD; ++i) {
            s += bn_shard[i * 128 + t];
            q += bn_shard[i * 128 + 64 + t];
        }
        float mean = s * (1.0f / N_NODES);
        float var = q * (1.0f / N_NODES) - mean * mean;
        float sc = gamma[t] * rsqrtf(var + BN_EPS);
        scale[t] = sc;
        shift[t] = beta[t] - mean * sc;
    }
    __syncthreads();
    for (int i = t; i < NSHARD * 128; i += 256) bn_shard[i] = 0.f;
}

// ---------------------------------------------------------------------------
// pool: 782 blocks x 128 rows, sharded accumulators (blockIdx&15, XCD-local)
__global__ __launch_bounds__(256) void k_pool(const _Float16* __restrict__ a2,
                                              const float* __restrict__ scale,
                                              const float* __restrict__ shift,
                                              const int* __restrict__ batch,
                                              float* __restrict__ pooled_sh,
                                              float* __restrict__ pcnt_sh) {
    int b = blockIdx.x, t = threadIdx.x;
    int c = t & 63;
    int rg = t >> 6;
    int base = b * BUCK_SZ;
    float sc = scale[c], sh = shift[c];
    float* pool_s = pooled_sh + (size_t)(b & (NSHARD - 1)) * (N_GRAPHS * 64);
    float* pcnt_s = pcnt_sh + (size_t)(b & (NSHARD - 1)) * N_GRAPHS;
    int gcur = -1;
    float acc = 0.f, cacc = 0.f;
    for (int i = rg; i < BUCK_SZ; i += 4) {
        int v = base + i;
        if (v >= N_NODES) break;
        int g = batch[v];
        if (g != gcur) {
            if (gcur >= 0) {
                atomicAdd(&pool_s[gcur * 64 + c], acc);
                if (c == 0) atomicAdd(&pcnt_s[gcur], cacc);
            }
            gcur = g;
            acc = 0.f;
            cacc = 0.f;
        }
        float h = fmaxf(sc * (float)a2[(size_t)v * 64 + c] + sh, 0.f);
        acc += h;
        cacc += 1.f;
    }
    if (gcur >= 0) {
        atomicAdd(&pool_s[gcur * 64 + c], acc);
        if (c == 0) atomicAdd(&pcnt_s[gcur], cacc);
    }
}

__global__ void k_out(const float* __restrict__ pooled_sh,
                      const float* __restrict__ pcnt_sh,
                      const float* __restrict__ Wout, const float* __restrict__ bout,
                      float* __restrict__ out) {
    int g = threadIdx.x;
    if (g < N_GRAPHS) {
        float cnt = 0.f;
        for (int s = 0; s < NSHARD; ++s) cnt += pcnt_sh[s * N_GRAPHS + g];
        cnt = fmaxf(cnt, 1.0f);
        float sum = 0.f;
        for (int c = 0; c < 64; ++c) {
            float p = 0.f;
            for (int s = 0; s < NSHARD; ++s)
                p += pooled_sh[(size_t)s * N_GRAPHS * 64 + g * 64 + c];
            sum += p * Wout[c];
        }
        out[g] = sum / cnt + bout[0];
    }
}

// ---------------------------------------------------------------------------
extern "C" void kernel_launch(void* const* d_in, const int* in_sizes, int n_in,
                              void* d_out, int out_size, void* d_ws, size_t ws_size,
                              hipStream_t stream) {
    const float* x    = (const float*)d_in[0];
    const int*   ei   = (const int*)d_in[1];
    const float* ew   = (const float*)d_in[2];
    const int*   batch= (const int*)d_in[3];
    const float* W1   = (const float*)d_in[4];
    const float* b1   = (const float*)d_in[5];
    const float* W2   = (const float*)d_in[6];
    const float* b2   = (const float*)d_in[7];
    const float* g1   = (const float*)d_in[8];
    const float* be1  = (const float*)d_in[9];
    const float* g2   = (const float*)d_in[10];
    const float* be2  = (const float*)d_in[11];
    const float* Wout = (const float*)d_in[12];
    const float* bout = (const float*)d_in[13];
    float* out = (float*)d_out;

    char* w = (char*)d_ws;
    size_t o = 0;
    auto alloc = [&](size_t bytes) -> void* {
        void* p = w + o;
        o = (o + bytes + 255) & ~(size_t)255;
        return p;
    };
    int*   cur     = (int*)alloc(NCNT * 4);
    int2*  nrange  = (int2*)alloc((size_t)N_NODES * 8);
    float* dinv    = (float*)alloc(N_NODES * 4);
    float* bnshard = (float*)alloc(NSHARD * 128 * 4);
    float* scale1  = (float*)alloc(64 * 4);
    float* shift1  = (float*)alloc(64 * 4);
    float* scale2  = (float*)alloc(64 * 4);
    float* shift2  = (float*)alloc(64 * 4);
    float* pooled  = (float*)alloc(NSHARD * N_GRAPHS * 64 * 4);
    float* pcnt    = (float*)alloc(NSHARD * N_GRAPHS * 4);
    uint2* ebuf2   = (uint2*)alloc((size_t)NBUCK * BCAP * 8);     // 28.8 MB
    // 38.4 MB region double-use: ebuf (slotted binning scratch, dead after
    // k_sortnorm), then two fp16 node buffers HA/HB (12.8 MB each).
    uint2* ebuf    = (uint2*)alloc((size_t)NCNT * SLOT_CAP * 8);  // 38.4 MB
    _Float16* bufHA = (_Float16*)ebuf;
    _Float16* bufHB = bufHA + (size_t)N_NODES * 64;
    if (o > ws_size) return;

    (void)hipMemsetAsync(bnshard, 0, NSHARD * 128 * 4, stream);
    (void)hipMemsetAsync(pooled, 0, NSHARD * N_GRAPHS * 64 * 4, stream);
    (void)hipMemsetAsync(pcnt, 0, NSHARD * N_GRAPHS * 4, stream);

    k_init<<<(NCNT + 255) / 256, 256, 0, stream>>>(cur);
    k_bin<<<BIN_BLOCKS, 512, 0, stream>>>(ei, ew, cur, ebuf);
    k_sortnorm<<<NBUCK, 256, 0, stream>>>(ebuf, cur, dinv, ebuf2, nrange);

    // layer 1: x (f32) -> h1' = dinv*(x@W1) (fp16) -> a1 (fp16) + BN1 stats
    k_gemm<128, false><<<(N_NODES + 127) / 128, 256, 0, stream>>>(x, W1, nullptr, nullptr, dinv, bufHA);
    k_agg<<<N_NODES / 32, 256, 0, stream>>>(bufHA, ebuf2, nrange, dinv, b1, bufHB, bnshard);
    k_bn_final<<<1, 256, 0, stream>>>(bnshard, g1, be1, scale1, shift1);

    // layer 2: a1 (fp16, fused BN+ReLU) -> h2' (fp16) -> a2 (fp16) + BN2 stats
    k_gemm<64, true><<<(N_NODES + 127) / 128, 256, 0, stream>>>(bufHB, W2, scale1, shift1, dinv, bufHA);
    k_agg<<<N_NODES / 32, 256, 0, stream>>>(bufHA, ebuf2, nrange, dinv, b2, bufHB, bnshard);
    k_bn_final<<<1, 256, 0, stream>>>(bnshard, g2, be2, scale2, shift2);

    // pool (fused BN2+ReLU, sharded accumulators) + output
    k_pool<<<NBUCK, 256, 0, stream>>>(bufHB, scale2, shift2, batch, pooled, pcnt);
    k_out<<<1, 64, 0, stream>>>(pooled, pcnt, Wout, bout, out);
}

// Round 16
// 353.109 us; speedup vs baseline: 1.1332x; 1.0707x over previous
//
#include <hip/hip_runtime.h>
#include <stdint.h>

#define N_NODES 100000
#define N_EDGES 3200000
#define IN_DIM 128
#define HID 64
#define N_GRAPHS 64
#define BN_EPS 1e-5f
#define NSHARD 16
#define BUCK_SH 7
#define BUCK_SZ 128
#define NBUCK ((N_NODES + BUCK_SZ - 1) / BUCK_SZ)   // 782
#define NCNT (NBUCK * 8)                             // 6256
#define BINB_EDGES 4096                              // edges per binning block
#define BIN_BLOCKS ((N_EDGES + BINB_EDGES - 1) / BINB_EDGES)  // 782
#define SLOT_CAP 768                                 // per-(stream,bucket) ebuf slot (mean 512, +11 sigma)
#define BCAP 4608                                    // per-bucket ebuf2 region (mean 4092, +8 sigma)
#define SORT_CAP (8 * SLOT_CAP)                      // 6144, always fits staged bucket
#define AGG_CAP 2048                                 // agg block edge stage (mean 1024)

// __builtin_nontemporal_load needs native (ext_vector) types, not HIP structs.
typedef float vf4 __attribute__((ext_vector_type(4)));
typedef int   vi4 __attribute__((ext_vector_type(4)));
typedef unsigned vu2 __attribute__((ext_vector_type(2)));
typedef _Float16 vh4 __attribute__((ext_vector_type(4)));

__device__ __forceinline__ float4 nt_f4(const float* p) {
    vf4 v = __builtin_nontemporal_load((const vf4*)p);
    return make_float4(v.x, v.y, v.z, v.w);
}
__device__ __forceinline__ int4 nt_i4(const int* p) {
    vi4 v = __builtin_nontemporal_load((const vi4*)p);
    return make_int4(v.x, v.y, v.z, v.w);
}
__device__ __forceinline__ uint2 nt_u2(const uint2* p) {
    vu2 v = __builtin_nontemporal_load((const vu2*)p);
    return make_uint2(v.x, v.y);
}
__device__ __forceinline__ vh4 nt_h4(const _Float16* p) {
    return __builtin_nontemporal_load((const vh4*)p);
}

// ---------------------------------------------------------------------------
// init per-(stream,bucket) cursors to fixed slot bases.
// LAYOUT cur[s*NBUCK + j]: stream s's cursors are a private 3.1 KB region ->
// reserve atomics XCD-local. Old layout cur[(j<<3)+s] put all 8 XCDs' cursors
// for bucket j in ONE 64B line -> ~600 serialized cross-XCD RMWs per line
// (~75 us, the rounds-13..15 invariant k_bin floor).
__global__ void k_init(int* __restrict__ cur) {
    int i = blockIdx.x * blockDim.x + threadIdx.x;
    if (i < NCNT) cur[i] = i * SLOT_CAP;
}

// bin: two NT passes over global, LDS = 782-int histogram, 512 threads.
// Pass A: histogram. Reserve: one XCD-LOCAL global atomic per non-empty
// bucket. Pass B: re-read, scatter from registers.
__global__ __launch_bounds__(512) void k_bin(const int* __restrict__ ei,
                                             const float* __restrict__ ew,
                                             int* __restrict__ cur,
                                             uint2* __restrict__ ebuf) {
    __shared__ int hist[NBUCK];
    int b = blockIdx.x, t = threadIdx.x;
    int s = b & 7;
    int base = b * BINB_EDGES;
    int n = min(BINB_EDGES, N_EDGES - base);
    for (int i = t; i < NBUCK; i += 512) hist[i] = 0;
    __syncthreads();
    // pass A: histogram of bucket ids (8 edges/thread = 2 chunks of 4)
#pragma unroll
    for (int k = 0; k < 2; ++k) {
        int ch = t + 512 * k;
        if (4 * ch < n) {
            int4 c4 = nt_i4(ei + N_EDGES + base + 4 * ch);
            atomicAdd(&hist[c4.x >> BUCK_SH], 1);
            atomicAdd(&hist[c4.y >> BUCK_SH], 1);
            atomicAdd(&hist[c4.z >> BUCK_SH], 1);
            atomicAdd(&hist[c4.w >> BUCK_SH], 1);
        }
    }
    __syncthreads();
    // reserve: hist[j] becomes the block's running cursor into slot (s, j)
    for (int j = t; j < NBUCK; j += 512) {
        int h = hist[j];
        if (h > 0) hist[j] = atomicAdd(&cur[s * NBUCK + j], h);
    }
    __syncthreads();
    // pass B: re-read (NT, L2/L3-cheap) and scatter from registers
#pragma unroll
    for (int k = 0; k < 2; ++k) {
        int ch = t + 512 * k;
        if (4 * ch < n) {
            int4 r4 = nt_i4(ei + base + 4 * ch);
            int4 c4 = nt_i4(ei + N_EDGES + base + 4 * ch);
            float4 w4 = nt_f4(ew + base + 4 * ch);
            int rr[4] = {r4.x, r4.y, r4.z, r4.w};
            int cc[4] = {c4.x, c4.y, c4.z, c4.w};
            float ww[4] = {w4.x, w4.y, w4.z, w4.w};
            int pos[4];
#pragma unroll
            for (int u = 0; u < 4; ++u)
                pos[u] = atomicAdd(&hist[cc[u] >> BUCK_SH], 1);
#pragma unroll
            for (int u = 0; u < 4; ++u)
                ebuf[pos[u]] = make_uint2(
                    (unsigned)(rr[u] | ((cc[u] & (BUCK_SZ - 1)) << 17)),
                    __float_as_uint(ww[u]));
        }
    }
}

// ---------------------------------------------------------------------------
// fused prep (dinv-factorized, slotted input), 512 threads: per bucket, read
// the 8 slots (lengths from cursors), stage in LDS, weighted degree ->
// dinv[c] (bucket-LOCAL, no cross-block race), dest histogram -> per-node
// ranges, scatter compacted into ebuf2[b*BCAP ...] with w' = w * dinv[c].
__global__ __launch_bounds__(512) void k_sortnorm(const uint2* __restrict__ ebuf,
                                                  const int* __restrict__ cur,
                                                  float* __restrict__ dinv,
                                                  uint2* __restrict__ ebuf2,
                                                  int2* __restrict__ nrange) {
    __shared__ uint2 se[SORT_CAP];
    __shared__ float sdi[BUCK_SZ];   // degree accum, then dinv
    __shared__ int scnt[BUCK_SZ];
    __shared__ int scur[BUCK_SZ];
    __shared__ int slen[8], soffc[8];
    int b = blockIdx.x, t = threadIdx.x;
    if (t < BUCK_SZ) { sdi[t] = 0.f; scnt[t] = 0; }
    if (t < 8) slen[t] = cur[t * NBUCK + b] - (t * NBUCK + b) * SLOT_CAP;
    __syncthreads();
    if (t == 0) {
        int run = 0;
#pragma unroll
        for (int s = 0; s < 8; ++s) { soffc[s] = run; run += slen[s]; }
    }
    __syncthreads();
    // pass 1: stage all 8 segments compactly + weighted degree + histogram
    for (int s = 0; s < 8; ++s) {
        int sb = (s * NBUCK + b) * SLOT_CAP;
        int len = slen[s];
        int off = soffc[s];
        for (int i = t; i < len; i += 512) {
            uint2 u = nt_u2(ebuf + sb + i);
            se[off + i] = u;
            int cl = u.x >> 17;
            atomicAdd(&sdi[cl], __uint_as_float(u.y));
            atomicAdd(&scnt[cl], 1);
        }
    }
    __syncthreads();
    int n = soffc[7] + slen[7];
    if (t < BUCK_SZ) {
        float di = rsqrtf(sdi[t] + 1.0f);   // +1 = self-loop weight
        int node = b * BUCK_SZ + t;
        if (node < N_NODES) dinv[node] = di;
        sdi[t] = di;
    }
    __syncthreads();
    // inclusive scan over 128 counts (all 512 threads hit barriers)
    for (int off = 1; off < BUCK_SZ; off <<= 1) {
        int x = 0;
        if (t < BUCK_SZ && t >= off) x = scnt[t - off];
        __syncthreads();
        if (t < BUCK_SZ) scnt[t] += x;
        __syncthreads();
    }
    if (t < BUCK_SZ) {
        int excl = (t > 0) ? scnt[t - 1] : 0;
        int cnt = scnt[t] - excl;
        scur[t] = b * BCAP + excl;
        int node = b * BUCK_SZ + t;
        if (node < N_NODES) nrange[node] = make_int2(b * BCAP + excl, b * BCAP + excl + cnt);
    }
    __syncthreads();
    // pass 2: scatter within bucket + w' = w * dinv[c]
    for (int i = t; i < n; i += 512) {
        uint2 u = se[i];
        int r = u.x & 131071;
        int cl = u.x >> 17;
        float nm = __uint_as_float(u.y) * sdi[cl];
        int p = atomicAdd(&scur[cl], 1);
        ebuf2[p] = make_uint2((unsigned)r, __float_as_uint(nm));
    }
}

// ---------------------------------------------------------------------------
// GEMM: out[n][c] = dinv[n] * sum_k in[n][k]*W[k][c]; fp16 output (h' = dinv*h).
// BNH: input is fp16 with fused BN+ReLU (layer 2); else f32 input (layer 1).
template <int K, bool BNH>
__global__ __launch_bounds__(256) void k_gemm(const void* __restrict__ in_,
                                              const float* __restrict__ W,
                                              const float* __restrict__ scale,
                                              const float* __restrict__ shift,
                                              const float* __restrict__ dinv,
                                              _Float16* __restrict__ out) {
    __shared__ float ws[K * 64];
    __shared__ float xs[32 * 132];
    __shared__ float ssc[64], ssh[64];
    int t = threadIdx.x;
    int nbase = blockIdx.x * 128;

#pragma unroll
    for (int i = 0; i < K / 16; ++i) {
        int idx = t + 256 * i;
        ((float4*)ws)[idx] = ((const float4*)W)[idx];
    }
    if (BNH && t < 64) { ssc[t] = scale[t]; ssh[t] = shift[t]; }

    int cg = t & 15;
    int ng = t >> 4;
    float acc[8][4];
#pragma unroll
    for (int i = 0; i < 8; ++i)
#pragma unroll
        for (int j = 0; j < 4; ++j) acc[i][j] = 0.f;

    for (int k0 = 0; k0 < K; k0 += 32) {
        __syncthreads();
#pragma unroll
        for (int i = 0; i < 4; ++i) {
            int idx = t + 256 * i;
            int row = idx >> 3;
            int kq = idx & 7;
            int node = nbase + row;
            float vv[4] = {0.f, 0.f, 0.f, 0.f};
            if (node < N_NODES) {
                if (BNH) {
                    vh4 v = nt_h4((const _Float16*)in_ + (size_t)node * K + k0 + kq * 4);
                    vv[0] = (float)v.x; vv[1] = (float)v.y;
                    vv[2] = (float)v.z; vv[3] = (float)v.w;
                } else {
                    float4 v = nt_f4((const float*)in_ + (size_t)node * K + k0 + kq * 4);
                    vv[0] = v.x; vv[1] = v.y; vv[2] = v.z; vv[3] = v.w;
                }
            }
#pragma unroll
            for (int u = 0; u < 4; ++u) {
                float val = vv[u];
                if (BNH) {
                    int k = k0 + kq * 4 + u;
                    val = fmaxf(ssc[k] * val + ssh[k], 0.f);
                }
                xs[(kq * 4 + u) * 132 + row] = val;
            }
        }
        __syncthreads();
#pragma unroll
        for (int k = 0; k < 32; ++k) {
            float4 wv = *(const float4*)(ws + (k0 + k) * 64 + cg * 4);
            float4 xa = *(const float4*)(xs + k * 132 + ng * 8);
            float4 xb = *(const float4*)(xs + k * 132 + ng * 8 + 4);
            float xv[8] = {xa.x, xa.y, xa.z, xa.w, xb.x, xb.y, xb.z, xb.w};
            float wvv[4] = {wv.x, wv.y, wv.z, wv.w};
#pragma unroll
            for (int i = 0; i < 8; ++i)
#pragma unroll
                for (int j = 0; j < 4; ++j) acc[i][j] += xv[i] * wvv[j];
        }
    }
#pragma unroll
    for (int i = 0; i < 8; ++i) {
        int node = nbase + ng * 8 + i;
        if (node < N_NODES) {
            float dv = dinv[node];
            vh4 o;
            o.x = (_Float16)(acc[i][0] * dv); o.y = (_Float16)(acc[i][1] * dv);
            o.z = (_Float16)(acc[i][2] * dv); o.w = (_Float16)(acc[i][3] * dv);
            *(vh4*)(out + (size_t)node * 64 + cg * 4) = o;
        }
    }
}

// ---------------------------------------------------------------------------
// CSR gather-aggregation: block stages its 32 nodes' contiguous edge metas in
// LDS; per-edge path is ds_read -> independent row gather, 16-deep pipelined.
//   out[v] = sum w'*h'[r] + dinv[v]*h'[v] + bias   (== GCN layer exactly)
__global__ __launch_bounds__(256) void k_agg(const _Float16* __restrict__ hin,
                                             const uint2* __restrict__ ebuf2,
                                             const int2* __restrict__ nrange,
                                             const float* __restrict__ dinv,
                                             const float* __restrict__ bias,
                                             _Float16* __restrict__ hout,
                                             float* __restrict__ bn_shard) {
    __shared__ uint2 sme[AGG_CAP];
    __shared__ float sm[4][64], qm[4][64];
    int b = blockIdx.x, t = threadIdx.x;
    int wave = t >> 6, lane = t & 63;
    int vbase0 = b * 32;                       // grid is exactly N_NODES/32
    int ebeg = nrange[vbase0].x;
    int eend = nrange[vbase0 + 31].y;
    int n = eend - ebeg;
    bool fit = (n <= AGG_CAP);
    if (fit) {
        for (int i = t; i < n; i += 256) sme[i] = nt_u2(ebuf2 + ebeg + i);
    }
    __syncthreads();

    float s = 0.f, q = 0.f;
    float bl = bias[lane];
    int vbase = vbase0 + wave * 8;
    for (int vi = 0; vi < 8; ++vi) {
        int v = vbase + vi;
        int2 be = nrange[v];
        int beg = be.x, end = be.y;
        float acc = 0.f;
        int j = beg;
        if (fit) {
            for (; j + 16 <= end; j += 16) {
                float fv[16], fn[16];
#pragma unroll
                for (int u = 0; u < 16; ++u) {
                    uint2 e = sme[j - ebeg + u];
                    fn[u] = __uint_as_float(e.y);
                    fv[u] = (float)hin[((size_t)e.x << 6) + lane];
                }
#pragma unroll
                for (int u = 0; u < 16; ++u) acc = fmaf(fn[u], fv[u], acc);
            }
            for (; j + 8 <= end; j += 8) {
                float fv[8], fn[8];
#pragma unroll
                for (int u = 0; u < 8; ++u) {
                    uint2 e = sme[j - ebeg + u];
                    fn[u] = __uint_as_float(e.y);
                    fv[u] = (float)hin[((size_t)e.x << 6) + lane];
                }
#pragma unroll
                for (int u = 0; u < 8; ++u) acc = fmaf(fn[u], fv[u], acc);
            }
            for (; j < end; ++j) {
                uint2 e = sme[j - ebeg];
                acc = fmaf(__uint_as_float(e.y),
                           (float)hin[((size_t)e.x << 6) + lane], acc);
            }
        } else {
            for (; j + 8 <= end; j += 8) {
                float fv[8], fn[8];
#pragma unroll
                for (int u = 0; u < 8; ++u) {
                    uint2 e = nt_u2(ebuf2 + j + u);
                    fn[u] = __uint_as_float(e.y);
                    fv[u] = (float)hin[((size_t)e.x << 6) + lane];
                }
#pragma unroll
                for (int u = 0; u < 8; ++u) acc = fmaf(fn[u], fv[u], acc);
            }
            for (; j < end; ++j) {
                uint2 e = nt_u2(ebuf2 + j);
                acc = fmaf(__uint_as_float(e.y),
                           (float)hin[((size_t)e.x << 6) + lane], acc);
            }
        }
        float dv = dinv[v];
        acc = fmaf(dv, (float)hin[((size_t)v << 6) + lane], acc);  // dinv*h' = dinv^2*h
        acc += bl;
        hout[((size_t)v << 6) + lane] = (_Float16)acc;
        s += acc;
        q += acc * acc;
    }
    sm[wave][lane] = s;
    qm[wave][lane] = q;
    __syncthreads();
    if (wave == 0) {
        float ts = sm[0][lane] + sm[1][lane] + sm[2][lane] + sm[3][lane];
        float tq = qm[0][lane] + qm[1][lane] + qm[2][lane] + qm[3][lane];
        float* shard = bn_shard + (blockIdx.x & (NSHARD - 1)) * 128;
        atomicAdd(&shard[lane], ts);
        atomicAdd(&shard[64 + lane], tq);
    }
}

// reduce BN shards -> scale/shift; re-zero shards for the next layer
__global__ void k_bn_final(float* __restrict__ bn_shard, const float* __restrict__ gamma,
                           const float* __restrict__ beta, float* __restrict__ scale,
                           float* __restrict__ shift) {
    int t = threadIdx.x;
    if (t < 64) {
        float s = 0.f, q = 0.f;
        for (int i = 0; i < NSHARD; ++i) {
            s += bn_shard[i * 128 + t];
            q += bn_shard[i * 128 + 64 + t];
        }
        float mean = s * (1.0f / N_NODES);
        float var = q * (1.0f / N_NODES) - mean * mean;
        float sc = gamma[t] * rsqrtf(var + BN_EPS);
        scale[t] = sc;
        shift[t] = beta[t] - mean * sc;
    }
    __syncthreads();
    for (int i = t; i < NSHARD * 128; i += 256) bn_shard[i] = 0.f;
}

// ---------------------------------------------------------------------------
// pool: 782 blocks x 128 rows, sharded accumulators (blockIdx&15, XCD-local)
__global__ __launch_bounds__(256) void k_pool(const _Float16* __restrict__ a2,
                                              const float* __restrict__ scale,
                                              const float* __restrict__ shift,
                                              const int* __restrict__ batch,
                                              float* __restrict__ pooled_sh,
                                              float* __restrict__ pcnt_sh) {
    int b = blockIdx.x, t = threadIdx.x;
    int c = t & 63;
    int rg = t >> 6;
    int base = b * BUCK_SZ;
    float sc = scale[c], sh = shift[c];
    float* pool_s = pooled_sh + (size_t)(b & (NSHARD - 1)) * (N_GRAPHS * 64);
    float* pcnt_s = pcnt_sh + (size_t)(b & (NSHARD - 1)) * N_GRAPHS;
    int gcur = -1;
    float acc = 0.f, cacc = 0.f;
    for (int i = rg; i < BUCK_SZ; i += 4) {
        int v = base + i;
        if (v >= N_NODES) break;
        int g = batch[v];
        if (g != gcur) {
            if (gcur >= 0) {
                atomicAdd(&pool_s[gcur * 64 + c], acc);
                if (c == 0) atomicAdd(&pcnt_s[gcur], cacc);
            }
            gcur = g;
            acc = 0.f;
            cacc = 0.f;
        }
        float h = fmaxf(sc * (float)a2[(size_t)v * 64 + c] + sh, 0.f);
        acc += h;
        cacc += 1.f;
    }
    if (gcur >= 0) {
        atomicAdd(&pool_s[gcur * 64 + c], acc);
        if (c == 0) atomicAdd(&pcnt_s[gcur], cacc);
    }
}

__global__ void k_out(const float* __restrict__ pooled_sh,
                      const float* __restrict__ pcnt_sh,
                      const float* __restrict__ Wout, const float* __restrict__ bout,
                      float* __restrict__ out) {
    int g = threadIdx.x;
    if (g < N_GRAPHS) {
        float cnt = 0.f;
        for (int s = 0; s < NSHARD; ++s) cnt += pcnt_sh[s * N_GRAPHS + g];
        cnt = fmaxf(cnt, 1.0f);
        float sum = 0.f;
        for (int c = 0; c < 64; ++c) {
            float p = 0.f;
            for (int s = 0; s < NSHARD; ++s)
                p += pooled_sh[(size_t)s * N_GRAPHS * 64 + g * 64 + c];
            sum += p * Wout[c];
        }
        out[g] = sum / cnt + bout[0];
    }
}

// ---------------------------------------------------------------------------
extern "C" void kernel_launch(void* const* d_in, const int* in_sizes, int n_in,
                              void* d_out, int out_size, void* d_ws, size_t ws_size,
                              hipStream_t stream) {
    const float* x    = (const float*)d_in[0];
    const int*   ei   = (const int*)d_in[1];
    const float* ew   = (const float*)d_in[2];
    const int*   batch= (const int*)d_in[3];
    const float* W1   = (const float*)d_in[4];
    const float* b1   = (const float*)d_in[5];
    const float* W2   = (const float*)d_in[6];
    const float* b2   = (const float*)d_in[7];
    const float* g1   = (const float*)d_in[8];
    const float* be1  = (const float*)d_in[9];
    const float* g2   = (const float*)d_in[10];
    const float* be2  = (const float*)d_in[11];
    const float* Wout = (const float*)d_in[12];
    const float* bout = (const float*)d_in[13];
    float* out = (float*)d_out;

    char* w = (char*)d_ws;
    size_t o = 0;
    auto alloc = [&](size_t bytes) -> void* {
        void* p = w + o;
        o = (o + bytes + 255) & ~(size_t)255;
        return p;
    };
    int*   cur     = (int*)alloc(NCNT * 4);
    int2*  nrange  = (int2*)alloc((size_t)N_NODES * 8);
    float* dinv    = (float*)alloc(N_NODES * 4);
    float* bnshard = (float*)alloc(NSHARD * 128 * 4);
    float* scale1  = (float*)alloc(64 * 4);
    float* shift1  = (float*)alloc(64 * 4);
    float* scale2  = (float*)alloc(64 * 4);
    float* shift2  = (float*)alloc(64 * 4);
    float* pooled  = (float*)alloc(NSHARD * N_GRAPHS * 64 * 4);
    float* pcnt    = (float*)alloc(NSHARD * N_GRAPHS * 4);
    uint2* ebuf2   = (uint2*)alloc((size_t)NBUCK * BCAP * 8);     // 28.8 MB
    // 38.4 MB region double-use: ebuf (slotted binning scratch, dead after
    // k_sortnorm), then two fp16 node buffers HA/HB (12.8 MB each).
    uint2* ebuf    = (uint2*)alloc((size_t)NCNT * SLOT_CAP * 8);  // 38.4 MB
    _Float16* bufHA = (_Float16*)ebuf;
    _Float16* bufHB = bufHA + (size_t)N_NODES * 64;
    if (o > ws_size) return;

    (void)hipMemsetAsync(bnshard, 0, NSHARD * 128 * 4, stream);
    (void)hipMemsetAsync(pooled, 0, NSHARD * N_GRAPHS * 64 * 4, stream);
    (void)hipMemsetAsync(pcnt, 0, NSHARD * N_GRAPHS * 4, stream);

    k_init<<<(NCNT + 255) / 256, 256, 0, stream>>>(cur);
    k_bin<<<BIN_BLOCKS, 512, 0, stream>>>(ei, ew, cur, ebuf);
    k_sortnorm<<<NBUCK, 512, 0, stream>>>(ebuf, cur, dinv, ebuf2, nrange);

    // layer 1: x (f32) -> h1' = dinv*(x@W1) (fp16) -> a1 (fp16) + BN1 stats
    k_gemm<128, false><<<(N_NODES + 127) / 128, 256, 0, stream>>>(x, W1, nullptr, nullptr, dinv, bufHA);
    k_agg<<<N_NODES / 32, 256, 0, stream>>>(bufHA, ebuf2, nrange, dinv, b1, bufHB, bnshard);
    k_bn_final<<<1, 256, 0, stream>>>(bnshard, g1, be1, scale1, shift1);

    // layer 2: a1 (fp16, fused BN+ReLU) -> h2' (fp16) -> a2 (fp16) + BN2 stats
    k_gemm<64, true><<<(N_NODES + 127) / 128, 256, 0, stream>>>(bufHB, W2, scale1, shift1, dinv, bufHA);
    k_agg<<<N_NODES / 32, 256, 0, stream>>>(bufHA, ebuf2, nrange, dinv, b2, bufHB, bnshard);
    k_bn_final<<<1, 256, 0, stream>>>(bnshard, g2, be2, scale2, shift2);

    // pool (fused BN2+ReLU, sharded accumulators) + output
    k_pool<<<NBUCK, 256, 0, stream>>>(bufHB, scale2, shift2, batch, pooled, pcnt);
    k_out<<<1, 64, 0, stream>>>(pooled, pcnt, Wout, bout, out);
}

// Round 17
// 350.816 us; speedup vs baseline: 1.1406x; 1.0065x over previous
//
#include <hip/hip_runtime.h>
#include <stdint.h>

#define N_NODES 100000
#define N_EDGES 3200000
#define IN_DIM 128
#define HID 64
#define N_GRAPHS 64
#define BN_EPS 1e-5f
#define NSHARD 16
#define BUCK_SH 7
#define BUCK_SZ 128
#define NBUCK ((N_NODES + BUCK_SZ - 1) / BUCK_SZ)   // 782
#define NCNT (NBUCK * 8)                             // 6256
#define BINB_EDGES 4096                              // edges per binning block
#define BIN_BLOCKS ((N_EDGES + BINB_EDGES - 1) / BINB_EDGES)  // 782
#define SLOT_CAP 768                                 // per-(stream,bucket) ebuf slot (mean 512, +11 sigma)
#define BCAP 4608                                    // per-bucket ebuf2 region (mean 4092, +8 sigma)
#define SORT_CAP (8 * SLOT_CAP)                      // 6144, always fits staged bucket
#define AGG_CAP 2048                                 // agg block edge stage (mean 1024, +32 sigma)

// __builtin_nontemporal_load needs native (ext_vector) types, not HIP structs.
typedef float vf4 __attribute__((ext_vector_type(4)));
typedef int   vi4 __attribute__((ext_vector_type(4)));
typedef unsigned vu2 __attribute__((ext_vector_type(2)));
typedef _Float16 vh4 __attribute__((ext_vector_type(4)));

__device__ __forceinline__ float4 nt_f4(const float* p) {
    vf4 v = __builtin_nontemporal_load((const vf4*)p);
    return make_float4(v.x, v.y, v.z, v.w);
}
__device__ __forceinline__ int4 nt_i4(const int* p) {
    vi4 v = __builtin_nontemporal_load((const vi4*)p);
    return make_int4(v.x, v.y, v.z, v.w);
}
__device__ __forceinline__ uint2 nt_u2(const uint2* p) {
    vu2 v = __builtin_nontemporal_load((const vu2*)p);
    return make_uint2(v.x, v.y);
}
__device__ __forceinline__ unsigned nt_u(const unsigned* p) {
    return __builtin_nontemporal_load(p);
}
__device__ __forceinline__ vh4 nt_h4(const _Float16* p) {
    return __builtin_nontemporal_load((const vh4*)p);
}

// packed edge: (r << 15) | fp16_bits(w)   [w >= 0 so sign bit is free; r < 2^17]
__device__ __forceinline__ unsigned pack_edge(unsigned r, _Float16 w) {
    unsigned short hb = __builtin_bit_cast(unsigned short, w);
    return (r << 15) | (unsigned)hb;
}
__device__ __forceinline__ float unpack_w(unsigned u) {
    return (float)__builtin_bit_cast(_Float16, (unsigned short)(u & 0x7FFFu));
}

// ---------------------------------------------------------------------------
// init per-(stream,bucket) cursors to fixed slot bases (cur[s*NBUCK+j]:
// XCD-local 3.1 KB regions — avoids the cross-XCD cursor-line ping-pong)
__global__ void k_init(int* __restrict__ cur) {
    int i = blockIdx.x * blockDim.x + threadIdx.x;
    if (i < NCNT) cur[i] = i * SLOT_CAP;
}

// bin: two NT passes over global, LDS = 782-int histogram, 512 threads.
__global__ __launch_bounds__(512) void k_bin(const int* __restrict__ ei,
                                             const float* __restrict__ ew,
                                             int* __restrict__ cur,
                                             uint2* __restrict__ ebuf) {
    __shared__ int hist[NBUCK];
    int b = blockIdx.x, t = threadIdx.x;
    int s = b & 7;
    int base = b * BINB_EDGES;
    int n = min(BINB_EDGES, N_EDGES - base);
    for (int i = t; i < NBUCK; i += 512) hist[i] = 0;
    __syncthreads();
#pragma unroll
    for (int k = 0; k < 2; ++k) {
        int ch = t + 512 * k;
        if (4 * ch < n) {
            int4 c4 = nt_i4(ei + N_EDGES + base + 4 * ch);
            atomicAdd(&hist[c4.x >> BUCK_SH], 1);
            atomicAdd(&hist[c4.y >> BUCK_SH], 1);
            atomicAdd(&hist[c4.z >> BUCK_SH], 1);
            atomicAdd(&hist[c4.w >> BUCK_SH], 1);
        }
    }
    __syncthreads();
    for (int j = t; j < NBUCK; j += 512) {
        int h = hist[j];
        if (h > 0) hist[j] = atomicAdd(&cur[s * NBUCK + j], h);
    }
    __syncthreads();
#pragma unroll
    for (int k = 0; k < 2; ++k) {
        int ch = t + 512 * k;
        if (4 * ch < n) {
            int4 r4 = nt_i4(ei + base + 4 * ch);
            int4 c4 = nt_i4(ei + N_EDGES + base + 4 * ch);
            float4 w4 = nt_f4(ew + base + 4 * ch);
            int rr[4] = {r4.x, r4.y, r4.z, r4.w};
            int cc[4] = {c4.x, c4.y, c4.z, c4.w};
            float ww[4] = {w4.x, w4.y, w4.z, w4.w};
            int pos[4];
#pragma unroll
            for (int u = 0; u < 4; ++u)
                pos[u] = atomicAdd(&hist[cc[u] >> BUCK_SH], 1);
#pragma unroll
            for (int u = 0; u < 4; ++u)
                ebuf[pos[u]] = make_uint2(
                    (unsigned)(rr[u] | ((cc[u] & (BUCK_SZ - 1)) << 17)),
                    __float_as_uint(ww[u]));
        }
    }
}

// ---------------------------------------------------------------------------
// fused prep, 512 threads: per bucket, stage the 8 slots (r|cl in 4B + fp16 w
// in 2B -> 38 KB, was 49), weighted degree (full-precision w) -> dinv[c],
// dest histogram -> per-node ranges, scatter 4-BYTE PACKED edges {r,fp16(w)}
// into ebuf2[b*BCAP ...]. dinv[c] is NOT folded into w: agg applies dinv[v]
// once per node at the end (out = dinv[v]*(sum w*h'[r] + h'[v]) + bias).
__global__ __launch_bounds__(512) void k_sortnorm(const uint2* __restrict__ ebuf,
                                                  const int* __restrict__ cur,
                                                  float* __restrict__ dinv,
                                                  unsigned* __restrict__ ebuf2,
                                                  int2* __restrict__ nrange) {
    __shared__ unsigned sex[SORT_CAP];   // r | cl<<17
    __shared__ _Float16 sew[SORT_CAP];   // fp16 weight
    __shared__ float sdi[BUCK_SZ];       // degree accum, then dinv
    __shared__ int scnt[BUCK_SZ];
    __shared__ int scur[BUCK_SZ];
    __shared__ int slen[8], soffc[8];
    int b = blockIdx.x, t = threadIdx.x;
    if (t < BUCK_SZ) { sdi[t] = 0.f; scnt[t] = 0; }
    if (t < 8) slen[t] = cur[t * NBUCK + b] - (t * NBUCK + b) * SLOT_CAP;
    __syncthreads();
    if (t == 0) {
        int run = 0;
#pragma unroll
        for (int s = 0; s < 8; ++s) { soffc[s] = run; run += slen[s]; }
    }
    __syncthreads();
    // pass 1: stage all 8 segments compactly + weighted degree + histogram
    for (int s = 0; s < 8; ++s) {
        int sb = (s * NBUCK + b) * SLOT_CAP;
        int len = slen[s];
        int off = soffc[s];
        for (int i = t; i < len; i += 512) {
            uint2 u = nt_u2(ebuf + sb + i);
            float wf = __uint_as_float(u.y);
            sex[off + i] = u.x;
            sew[off + i] = (_Float16)wf;
            int cl = u.x >> 17;
            atomicAdd(&sdi[cl], wf);
            atomicAdd(&scnt[cl], 1);
        }
    }
    __syncthreads();
    int n = soffc[7] + slen[7];
    if (t < BUCK_SZ) {
        float di = rsqrtf(sdi[t] + 1.0f);   // +1 = self-loop weight
        int node = b * BUCK_SZ + t;
        if (node < N_NODES) dinv[node] = di;
    }
    __syncthreads();
    // inclusive scan over 128 counts (all 512 threads hit barriers)
    for (int off = 1; off < BUCK_SZ; off <<= 1) {
        int x = 0;
        if (t < BUCK_SZ && t >= off) x = scnt[t - off];
        __syncthreads();
        if (t < BUCK_SZ) scnt[t] += x;
        __syncthreads();
    }
    if (t < BUCK_SZ) {
        int excl = (t > 0) ? scnt[t - 1] : 0;
        int cnt = scnt[t] - excl;
        scur[t] = b * BCAP + excl;
        int node = b * BUCK_SZ + t;
        if (node < N_NODES) nrange[node] = make_int2(b * BCAP + excl, b * BCAP + excl + cnt);
    }
    __syncthreads();
    // pass 2: scatter packed 4B edges within bucket
    for (int i = t; i < n; i += 512) {
        unsigned x = sex[i];
        unsigned r = x & 131071u;
        int cl = x >> 17;
        int p = atomicAdd(&scur[cl], 1);
        ebuf2[p] = pack_edge(r, sew[i]);
    }
}

// ---------------------------------------------------------------------------
// GEMM: out[n][c] = dinv[n] * sum_k in[n][k]*W[k][c]; fp16 output (h' = dinv*h).
// BNH: input is fp16 with fused BN+ReLU (layer 2); else f32 input (layer 1).
template <int K, bool BNH>
__global__ __launch_bounds__(256) void k_gemm(const void* __restrict__ in_,
                                              const float* __restrict__ W,
                                              const float* __restrict__ scale,
                                              const float* __restrict__ shift,
                                              const float* __restrict__ dinv,
                                              _Float16* __restrict__ out) {
    __shared__ float ws[K * 64];
    __shared__ float xs[32 * 132];
    __shared__ float ssc[64], ssh[64];
    int t = threadIdx.x;
    int nbase = blockIdx.x * 128;

#pragma unroll
    for (int i = 0; i < K / 16; ++i) {
        int idx = t + 256 * i;
        ((float4*)ws)[idx] = ((const float4*)W)[idx];
    }
    if (BNH && t < 64) { ssc[t] = scale[t]; ssh[t] = shift[t]; }

    int cg = t & 15;
    int ng = t >> 4;
    float acc[8][4];
#pragma unroll
    for (int i = 0; i < 8; ++i)
#pragma unroll
        for (int j = 0; j < 4; ++j) acc[i][j] = 0.f;

    for (int k0 = 0; k0 < K; k0 += 32) {
        __syncthreads();
#pragma unroll
        for (int i = 0; i < 4; ++i) {
            int idx = t + 256 * i;
            int row = idx >> 3;
            int kq = idx & 7;
            int node = nbase + row;
            float vv[4] = {0.f, 0.f, 0.f, 0.f};
            if (node < N_NODES) {
                if (BNH) {
                    vh4 v = nt_h4((const _Float16*)in_ + (size_t)node * K + k0 + kq * 4);
                    vv[0] = (float)v.x; vv[1] = (float)v.y;
                    vv[2] = (float)v.z; vv[3] = (float)v.w;
                } else {
                    float4 v = nt_f4((const float*)in_ + (size_t)node * K + k0 + kq * 4);
                    vv[0] = v.x; vv[1] = v.y; vv[2] = v.z; vv[3] = v.w;
                }
            }
#pragma unroll
            for (int u = 0; u < 4; ++u) {
                float val = vv[u];
                if (BNH) {
                    int k = k0 + kq * 4 + u;
                    val = fmaxf(ssc[k] * val + ssh[k], 0.f);
                }
                xs[(kq * 4 + u) * 132 + row] = val;
            }
        }
        __syncthreads();
#pragma unroll
        for (int k = 0; k < 32; ++k) {
            float4 wv = *(const float4*)(ws + (k0 + k) * 64 + cg * 4);
            float4 xa = *(const float4*)(xs + k * 132 + ng * 8);
            float4 xb = *(const float4*)(xs + k * 132 + ng * 8 + 4);
            float xv[8] = {xa.x, xa.y, xa.z, xa.w, xb.x, xb.y, xb.z, xb.w};
            float wvv[4] = {wv.x, wv.y, wv.z, wv.w};
#pragma unroll
            for (int i = 0; i < 8; ++i)
#pragma unroll
                for (int j = 0; j < 4; ++j) acc[i][j] += xv[i] * wvv[j];
        }
    }
#pragma unroll
    for (int i = 0; i < 8; ++i) {
        int node = nbase + ng * 8 + i;
        if (node < N_NODES) {
            float dv = dinv[node];
            vh4 o;
            o.x = (_Float16)(acc[i][0] * dv); o.y = (_Float16)(acc[i][1] * dv);
            o.z = (_Float16)(acc[i][2] * dv); o.w = (_Float16)(acc[i][3] * dv);
            *(vh4*)(out + (size_t)node * 64 + cg * 4) = o;
        }
    }
}

// ---------------------------------------------------------------------------
// CSR gather-aggregation: block stages its 32 nodes' contiguous 4B packed
// edges in LDS (8 KB); per-edge path is ds_read -> independent row gather,
// 16-deep pipelined.  out[v] = dinv[v]*(sum w*h'[r] + h'[v]) + bias
__global__ __launch_bounds__(256) void k_agg(const _Float16* __restrict__ hin,
                                             const unsigned* __restrict__ ebuf2,
                                             const int2* __restrict__ nrange,
                                             const float* __restrict__ dinv,
                                             const float* __restrict__ bias,
                                             _Float16* __restrict__ hout,
                                             float* __restrict__ bn_shard) {
    __shared__ unsigned sme[AGG_CAP];
    __shared__ float sm[4][64], qm[4][64];
    int b = blockIdx.x, t = threadIdx.x;
    int wave = t >> 6, lane = t & 63;
    int vbase0 = b * 32;                       // grid is exactly N_NODES/32
    int ebeg = nrange[vbase0].x;
    int eend = nrange[vbase0 + 31].y;
    int n = eend - ebeg;
    bool fit = (n <= AGG_CAP);
    if (fit) {
        for (int i = t; i < n; i += 256) sme[i] = nt_u(ebuf2 + ebeg + i);
    }
    __syncthreads();

    float s = 0.f, q = 0.f;
    float bl = bias[lane];
    int vbase = vbase0 + wave * 8;
    for (int vi = 0; vi < 8; ++vi) {
        int v = vbase + vi;
        int2 be = nrange[v];
        int beg = be.x, end = be.y;
        float acc = 0.f;
        int j = beg;
        if (fit) {
            for (; j + 16 <= end; j += 16) {
                float fv[16], fn[16];
#pragma unroll
                for (int u = 0; u < 16; ++u) {
                    unsigned e = sme[j - ebeg + u];
                    fn[u] = unpack_w(e);
                    fv[u] = (float)hin[((size_t)(e >> 15) << 6) + lane];
                }
#pragma unroll
                for (int u = 0; u < 16; ++u) acc = fmaf(fn[u], fv[u], acc);
            }
            for (; j + 8 <= end; j += 8) {
                float fv[8], fn[8];
#pragma unroll
                for (int u = 0; u < 8; ++u) {
                    unsigned e = sme[j - ebeg + u];
                    fn[u] = unpack_w(e);
                    fv[u] = (float)hin[((size_t)(e >> 15) << 6) + lane];
                }
#pragma unroll
                for (int u = 0; u < 8; ++u) acc = fmaf(fn[u], fv[u], acc);
            }
            for (; j < end; ++j) {
                unsigned e = sme[j - ebeg];
                acc = fmaf(unpack_w(e),
                           (float)hin[((size_t)(e >> 15) << 6) + lane], acc);
            }
        } else {
            for (; j + 8 <= end; j += 8) {
                float fv[8], fn[8];
#pragma unroll
                for (int u = 0; u < 8; ++u) {
                    unsigned e = nt_u(ebuf2 + j + u);
                    fn[u] = unpack_w(e);
                    fv[u] = (float)hin[((size_t)(e >> 15) << 6) + lane];
                }
#pragma unroll
                for (int u = 0; u < 8; ++u) acc = fmaf(fn[u], fv[u], acc);
            }
            for (; j < end; ++j) {
                unsigned e = nt_u(ebuf2 + j);
                acc = fmaf(unpack_w(e),
                           (float)hin[((size_t)(e >> 15) << 6) + lane], acc);
            }
        }
        // self-loop then single dinv[v] scale (dinv[c] factored out of edges)
        acc += (float)hin[((size_t)v << 6) + lane];
        acc = fmaf(dinv[v], acc, bl);
        hout[((size_t)v << 6) + lane] = (_Float16)acc;
        s += acc;
        q += acc * acc;
    }
    sm[wave][lane] = s;
    qm[wave][lane] = q;
    __syncthreads();
    if (wave == 0) {
        float ts = sm[0][lane] + sm[1][lane] + sm[2][lane] + sm[3][lane];
        float tq = qm[0][lane] + qm[1][lane] + qm[2][lane] + qm[3][lane];
        float* shard = bn_shard + (blockIdx.x & (NSHARD - 1)) * 128;
        atomicAdd(&shard[lane], ts);
        atomicAdd(&shard[64 + lane], tq);
    }
}

// reduce BN shards -> scale/shift; re-zero shards for the next layer
__global__ void k_bn_final(float* __restrict__ bn_shard, const float* __restrict__ gamma,
                           const float* __restrict__ beta, float* __restrict__ scale,
                           float* __restrict__ shift) {
    int t = threadIdx.x;
    if (t < 64) {
        float s = 0.f, q = 0.f;
        for (int i = 0; i < NSHARD; ++i) {
            s += bn_shard[i * 128 + t];
            q += bn_shard[i * 128 + 64 + t];
        }
        float mean = s * (1.0f / N_NODES);
        float var = q * (1.0f / N_NODES) - mean * mean;
        float sc = gamma[t] * rsqrtf(var + BN_EPS);
        scale[t] = sc;
        shift[t] = beta[t] - mean * sc;
    }
    __syncthreads();
    for (int i = t; i < NSHARD * 128; i += 256) bn_shard[i] = 0.f;
}

// ---------------------------------------------------------------------------
// pool: 782 blocks x 128 rows, sharded accumulators (blockIdx&15, XCD-local)
__global__ __launch_bounds__(256) void k_pool(const _Float16* __restrict__ a2,
                                              const float* __restrict__ scale,
                                              const float* __restrict__ shift,
                                              const int* __restrict__ batch,
                                              float* __restrict__ pooled_sh,
                                              float* __restrict__ pcnt_sh) {
    int b = blockIdx.x, t = threadIdx.x;
    int c = t & 63;
    int rg = t >> 6;
    int base = b * BUCK_SZ;
    float sc = scale[c], sh = shift[c];
    float* pool_s = pooled_sh + (size_t)(b & (NSHARD - 1)) * (N_GRAPHS * 64);
    float* pcnt_s = pcnt_sh + (size_t)(b & (NSHARD - 1)) * N_GRAPHS;
    int gcur = -1;
    float acc = 0.f, cacc = 0.f;
    for (int i = rg; i < BUCK_SZ; i += 4) {
        int v = base + i;
        if (v >= N_NODES) break;
        int g = batch[v];
        if (g != gcur) {
            if (gcur >= 0) {
                atomicAdd(&pool_s[gcur * 64 + c], acc);
                if (c == 0) atomicAdd(&pcnt_s[gcur], cacc);
            }
            gcur = g;
            acc = 0.f;
            cacc = 0.f;
        }
        float h = fmaxf(sc * (float)a2[(size_t)v * 64 + c] + sh, 0.f);
        acc += h;
        cacc += 1.f;
    }
    if (gcur >= 0) {
        atomicAdd(&pool_s[gcur * 64 + c], acc);
        if (c == 0) atomicAdd(&pcnt_s[gcur], cacc);
    }
}

__global__ void k_out(const float* __restrict__ pooled_sh,
                      const float* __restrict__ pcnt_sh,
                      const float* __restrict__ Wout, const float* __restrict__ bout,
                      float* __restrict__ out) {
    int g = threadIdx.x;
    if (g < N_GRAPHS) {
        float cnt = 0.f;
        for (int s = 0; s < NSHARD; ++s) cnt += pcnt_sh[s * N_GRAPHS + g];
        cnt = fmaxf(cnt, 1.0f);
        float sum = 0.f;
        for (int c = 0; c < 64; ++c) {
            float p = 0.f;
            for (int s = 0; s < NSHARD; ++s)
                p += pooled_sh[(size_t)s * N_GRAPHS * 64 + g * 64 + c];
            sum += p * Wout[c];
        }
        out[g] = sum / cnt + bout[0];
    }
}

// ---------------------------------------------------------------------------
extern "C" void kernel_launch(void* const* d_in, const int* in_sizes, int n_in,
                              void* d_out, int out_size, void* d_ws, size_t ws_size,
                              hipStream_t stream) {
    const float* x    = (const float*)d_in[0];
    const int*   ei   = (const int*)d_in[1];
    const float* ew   = (const float*)d_in[2];
    const int*   batch= (const int*)d_in[3];
    const float* W1   = (const float*)d_in[4];
    const float* b1   = (const float*)d_in[5];
    const float* W2   = (const float*)d_in[6];
    const float* b2   = (const float*)d_in[7];
    const float* g1   = (const float*)d_in[8];
    const float* be1  = (const float*)d_in[9];
    const float* g2   = (const float*)d_in[10];
    const float* be2  = (const float*)d_in[11];
    const float* Wout = (const float*)d_in[12];
    const float* bout = (const float*)d_in[13];
    float* out = (float*)d_out;

    char* w = (char*)d_ws;
    size_t o = 0;
    auto alloc = [&](size_t bytes) -> void* {
        void* p = w + o;
        o = (o + bytes + 255) & ~(size_t)255;
        return p;
    };
    int*   cur     = (int*)alloc(NCNT * 4);
    int2*  nrange  = (int2*)alloc((size_t)N_NODES * 8);
    float* dinv    = (float*)alloc(N_NODES * 4);
    float* bnshard = (float*)alloc(NSHARD * 128 * 4);
    float* scale1  = (float*)alloc(64 * 4);
    float* shift1  = (float*)alloc(64 * 4);
    float* scale2  = (float*)alloc(64 * 4);
    float* shift2  = (float*)alloc(64 * 4);
    float* pooled  = (float*)alloc(NSHARD * N_GRAPHS * 64 * 4);
    float* pcnt    = (float*)alloc(NSHARD * N_GRAPHS * 4);
    unsigned* ebuf2 = (unsigned*)alloc((size_t)NBUCK * BCAP * 4);  // 14.4 MB
    // 38.4 MB region double-use: ebuf (slotted binning scratch, dead after
    // k_sortnorm), then two fp16 node buffers HA/HB (12.8 MB each).
    uint2* ebuf    = (uint2*)alloc((size_t)NCNT * SLOT_CAP * 8);   // 38.4 MB
    _Float16* bufHA = (_Float16*)ebuf;
    _Float16* bufHB = bufHA + (size_t)N_NODES * 64;
    if (o > ws_size) return;

    (void)hipMemsetAsync(bnshard, 0, NSHARD * 128 * 4, stream);
    (void)hipMemsetAsync(pooled, 0, NSHARD * N_GRAPHS * 64 * 4, stream);
    (void)hipMemsetAsync(pcnt, 0, NSHARD * N_GRAPHS * 4, stream);

    k_init<<<(NCNT + 255) / 256, 256, 0, stream>>>(cur);
    k_bin<<<BIN_BLOCKS, 512, 0, stream>>>(ei, ew, cur, ebuf);
    k_sortnorm<<<NBUCK, 512, 0, stream>>>(ebuf, cur, dinv, ebuf2, nrange);

    // layer 1: x (f32) -> h1' = dinv*(x@W1) (fp16) -> a1 (fp16) + BN1 stats
    k_gemm<128, false><<<(N_NODES + 127) / 128, 256, 0, stream>>>(x, W1, nullptr, nullptr, dinv, bufHA);
    k_agg<<<N_NODES / 32, 256, 0, stream>>>(bufHA, ebuf2, nrange, dinv, b1, bufHB, bnshard);
    k_bn_final<<<1, 256, 0, stream>>>(bnshard, g1, be1, scale1, shift1);

    // layer 2: a1 (fp16, fused BN+ReLU) -> h2' (fp16) -> a2 (fp16) + BN2 stats
    k_gemm<64, true><<<(N_NODES + 127) / 128, 256, 0, stream>>>(bufHB, W2, scale1, shift1, dinv, bufHA);
    k_agg<<<N_NODES / 32, 256, 0, stream>>>(bufHA, ebuf2, nrange, dinv, b2, bufHB, bnshard);
    k_bn_final<<<1, 256, 0, stream>>>(bnshard, g2, be2, scale2, shift2);

    // pool (fused BN2+ReLU, sharded accumulators) + output
    k_pool<<<NBUCK, 256, 0, stream>>>(bufHB, scale2, shift2, batch, pooled, pcnt);
    k_out<<<1, 64, 0, stream>>>(pooled, pcnt, Wout, bout, out);
}

// Round 18
// 349.273 us; speedup vs baseline: 1.1457x; 1.0044x over previous
//
#include <hip/hip_runtime.h>
#include <stdint.h>

#define N_NODES 100000
#define N_EDGES 3200000
#define IN_DIM 128
#define HID 64
#define N_GRAPHS 64
#define BN_EPS 1e-5f
#define NSHARD 16
#define BUCK_SH 7
#define BUCK_SZ 128
#define NBUCK ((N_NODES + BUCK_SZ - 1) / BUCK_SZ)   // 782
#define NCNT (NBUCK * 8)                             // 6256
#define BINB_EDGES 4096                              // edges per binning block
#define BIN_BLOCKS ((N_EDGES + BINB_EDGES - 1) / BINB_EDGES)  // 782
#define SLOT_CAP 768                                 // per-(stream,bucket) ebuf slot
#define BCAP 4608                                    // per-bucket ebuf2 region
#define SORT_CAP (8 * SLOT_CAP)                      // 6144
#define AGG_CAP 2048                                 // agg block edge stage (mean 1024)

// __builtin_nontemporal_load needs native (ext_vector) types, not HIP structs.
typedef float vf4 __attribute__((ext_vector_type(4)));
typedef int   vi4 __attribute__((ext_vector_type(4)));
typedef unsigned vu2 __attribute__((ext_vector_type(2)));
typedef _Float16 vh4 __attribute__((ext_vector_type(4)));

__device__ __forceinline__ float4 nt_f4(const float* p) {
    vf4 v = __builtin_nontemporal_load((const vf4*)p);
    return make_float4(v.x, v.y, v.z, v.w);
}
__device__ __forceinline__ int4 nt_i4(const int* p) {
    vi4 v = __builtin_nontemporal_load((const vi4*)p);
    return make_int4(v.x, v.y, v.z, v.w);
}
__device__ __forceinline__ uint2 nt_u2(const uint2* p) {
    vu2 v = __builtin_nontemporal_load((const vu2*)p);
    return make_uint2(v.x, v.y);
}
__device__ __forceinline__ unsigned nt_u(const unsigned* p) {
    return __builtin_nontemporal_load(p);
}
__device__ __forceinline__ vh4 nt_h4(const _Float16* p) {
    return __builtin_nontemporal_load((const vh4*)p);
}

// packed edge: (r << 15) | fp16_bits(w)   [w >= 0 so sign bit free; r < 2^17]
__device__ __forceinline__ unsigned pack_edge(unsigned r, _Float16 w) {
    unsigned short hb = __builtin_bit_cast(unsigned short, w);
    return (r << 15) | (unsigned)hb;
}
__device__ __forceinline__ float unpack_w(unsigned u) {
    return (float)__builtin_bit_cast(_Float16, (unsigned short)(u & 0x7FFFu));
}
__device__ __forceinline__ float f16lo(unsigned u) {
    return (float)__builtin_bit_cast(_Float16, (unsigned short)(u & 0xFFFFu));
}
__device__ __forceinline__ float f16hi(unsigned u) {
    return (float)__builtin_bit_cast(_Float16, (unsigned short)(u >> 16));
}
__device__ __forceinline__ unsigned packh2(float a, float b) {
    unsigned short la = __builtin_bit_cast(unsigned short, (_Float16)a);
    unsigned short lb = __builtin_bit_cast(unsigned short, (_Float16)b);
    return (unsigned)la | ((unsigned)lb << 16);
}

// ---------------------------------------------------------------------------
// init per-(stream,bucket) cursors to fixed slot bases (cur[s*NBUCK+j]:
// XCD-local 3.1 KB regions — avoids cross-XCD cursor-line ping-pong)
__global__ void k_init(int* __restrict__ cur) {
    int i = blockIdx.x * blockDim.x + threadIdx.x;
    if (i < NCNT) cur[i] = i * SLOT_CAP;
}

// bin: two NT passes over global, LDS = 782-int histogram, 512 threads.
__global__ __launch_bounds__(512) void k_bin(const int* __restrict__ ei,
                                             const float* __restrict__ ew,
                                             int* __restrict__ cur,
                                             uint2* __restrict__ ebuf) {
    __shared__ int hist[NBUCK];
    int b = blockIdx.x, t = threadIdx.x;
    int s = b & 7;
    int base = b * BINB_EDGES;
    int n = min(BINB_EDGES, N_EDGES - base);
    for (int i = t; i < NBUCK; i += 512) hist[i] = 0;
    __syncthreads();
#pragma unroll
    for (int k = 0; k < 2; ++k) {
        int ch = t + 512 * k;
        if (4 * ch < n) {
            int4 c4 = nt_i4(ei + N_EDGES + base + 4 * ch);
            atomicAdd(&hist[c4.x >> BUCK_SH], 1);
            atomicAdd(&hist[c4.y >> BUCK_SH], 1);
            atomicAdd(&hist[c4.z >> BUCK_SH], 1);
            atomicAdd(&hist[c4.w >> BUCK_SH], 1);
        }
    }
    __syncthreads();
    for (int j = t; j < NBUCK; j += 512) {
        int h = hist[j];
        if (h > 0) hist[j] = atomicAdd(&cur[s * NBUCK + j], h);
    }
    __syncthreads();
#pragma unroll
    for (int k = 0; k < 2; ++k) {
        int ch = t + 512 * k;
        if (4 * ch < n) {
            int4 r4 = nt_i4(ei + base + 4 * ch);
            int4 c4 = nt_i4(ei + N_EDGES + base + 4 * ch);
            float4 w4 = nt_f4(ew + base + 4 * ch);
            int rr[4] = {r4.x, r4.y, r4.z, r4.w};
            int cc[4] = {c4.x, c4.y, c4.z, c4.w};
            float ww[4] = {w4.x, w4.y, w4.z, w4.w};
            int pos[4];
#pragma unroll
            for (int u = 0; u < 4; ++u)
                pos[u] = atomicAdd(&hist[cc[u] >> BUCK_SH], 1);
#pragma unroll
            for (int u = 0; u < 4; ++u)
                ebuf[pos[u]] = make_uint2(
                    (unsigned)(rr[u] | ((cc[u] & (BUCK_SZ - 1)) << 17)),
                    __float_as_uint(ww[u]));
        }
    }
}

// ---------------------------------------------------------------------------
// fused prep, 512 threads: per bucket, stage 8 slots, weighted degree (full
// precision) -> dinv[c], dest histogram -> per-node ranges, scatter 4-byte
// packed edges {r, fp16(w)}. dinv applied per-node in agg epilogue.
__global__ __launch_bounds__(512) void k_sortnorm(const uint2* __restrict__ ebuf,
                                                  const int* __restrict__ cur,
                                                  float* __restrict__ dinv,
                                                  unsigned* __restrict__ ebuf2,
                                                  int2* __restrict__ nrange) {
    __shared__ unsigned sex[SORT_CAP];   // r | cl<<17
    __shared__ _Float16 sew[SORT_CAP];   // fp16 weight
    __shared__ float sdi[BUCK_SZ];       // degree accum, then dinv
    __shared__ int scnt[BUCK_SZ];
    __shared__ int scur[BUCK_SZ];
    __shared__ int slen[8], soffc[8];
    int b = blockIdx.x, t = threadIdx.x;
    if (t < BUCK_SZ) { sdi[t] = 0.f; scnt[t] = 0; }
    if (t < 8) slen[t] = cur[t * NBUCK + b] - (t * NBUCK + b) * SLOT_CAP;
    __syncthreads();
    if (t == 0) {
        int run = 0;
#pragma unroll
        for (int s = 0; s < 8; ++s) { soffc[s] = run; run += slen[s]; }
    }
    __syncthreads();
    for (int s = 0; s < 8; ++s) {
        int sb = (s * NBUCK + b) * SLOT_CAP;
        int len = slen[s];
        int off = soffc[s];
        for (int i = t; i < len; i += 512) {
            uint2 u = nt_u2(ebuf + sb + i);
            float wf = __uint_as_float(u.y);
            sex[off + i] = u.x;
            sew[off + i] = (_Float16)wf;
            int cl = u.x >> 17;
            atomicAdd(&sdi[cl], wf);
            atomicAdd(&scnt[cl], 1);
        }
    }
    __syncthreads();
    int n = soffc[7] + slen[7];
    if (t < BUCK_SZ) {
        float di = rsqrtf(sdi[t] + 1.0f);   // +1 = self-loop weight
        int node = b * BUCK_SZ + t;
        if (node < N_NODES) dinv[node] = di;
    }
    __syncthreads();
    for (int off = 1; off < BUCK_SZ; off <<= 1) {
        int x = 0;
        if (t < BUCK_SZ && t >= off) x = scnt[t - off];
        __syncthreads();
        if (t < BUCK_SZ) scnt[t] += x;
        __syncthreads();
    }
    if (t < BUCK_SZ) {
        int excl = (t > 0) ? scnt[t - 1] : 0;
        int cnt = scnt[t] - excl;
        scur[t] = b * BCAP + excl;
        int node = b * BUCK_SZ + t;
        if (node < N_NODES) nrange[node] = make_int2(b * BCAP + excl, b * BCAP + excl + cnt);
    }
    __syncthreads();
    for (int i = t; i < n; i += 512) {
        unsigned x = sex[i];
        unsigned r = x & 131071u;
        int cl = x >> 17;
        int p = atomicAdd(&scur[cl], 1);
        ebuf2[p] = pack_edge(r, sew[i]);
    }
}

// ---------------------------------------------------------------------------
// GEMM: out[n][c] = dinv[n] * sum_k in[n][k]*W[k][c]; fp16 output (h' = dinv*h).
template <int K, bool BNH>
__global__ __launch_bounds__(256) void k_gemm(const void* __restrict__ in_,
                                              const float* __restrict__ W,
                                              const float* __restrict__ scale,
                                              const float* __restrict__ shift,
                                              const float* __restrict__ dinv,
                                              _Float16* __restrict__ out) {
    __shared__ float ws[K * 64];
    __shared__ float xs[32 * 132];
    __shared__ float ssc[64], ssh[64];
    int t = threadIdx.x;
    int nbase = blockIdx.x * 128;

#pragma unroll
    for (int i = 0; i < K / 16; ++i) {
        int idx = t + 256 * i;
        ((float4*)ws)[idx] = ((const float4*)W)[idx];
    }
    if (BNH && t < 64) { ssc[t] = scale[t]; ssh[t] = shift[t]; }

    int cg = t & 15;
    int ng = t >> 4;
    float acc[8][4];
#pragma unroll
    for (int i = 0; i < 8; ++i)
#pragma unroll
        for (int j = 0; j < 4; ++j) acc[i][j] = 0.f;

    for (int k0 = 0; k0 < K; k0 += 32) {
        __syncthreads();
#pragma unroll
        for (int i = 0; i < 4; ++i) {
            int idx = t + 256 * i;
            int row = idx >> 3;
            int kq = idx & 7;
            int node = nbase + row;
            float vv[4] = {0.f, 0.f, 0.f, 0.f};
            if (node < N_NODES) {
                if (BNH) {
                    vh4 v = nt_h4((const _Float16*)in_ + (size_t)node * K + k0 + kq * 4);
                    vv[0] = (float)v.x; vv[1] = (float)v.y;
                    vv[2] = (float)v.z; vv[3] = (float)v.w;
                } else {
                    float4 v = nt_f4((const float*)in_ + (size_t)node * K + k0 + kq * 4);
                    vv[0] = v.x; vv[1] = v.y; vv[2] = v.z; vv[3] = v.w;
                }
            }
#pragma unroll
            for (int u = 0; u < 4; ++u) {
                float val = vv[u];
                if (BNH) {
                    int k = k0 + kq * 4 + u;
                    val = fmaxf(ssc[k] * val + ssh[k], 0.f);
                }
                xs[(kq * 4 + u) * 132 + row] = val;
            }
        }
        __syncthreads();
#pragma unroll
        for (int k = 0; k < 32; ++k) {
            float4 wv = *(const float4*)(ws + (k0 + k) * 64 + cg * 4);
            float4 xa = *(const float4*)(xs + k * 132 + ng * 8);
            float4 xb = *(const float4*)(xs + k * 132 + ng * 8 + 4);
            float xv[8] = {xa.x, xa.y, xa.z, xa.w, xb.x, xb.y, xb.z, xb.w};
            float wvv[4] = {wv.x, wv.y, wv.z, wv.w};
#pragma unroll
            for (int i = 0; i < 8; ++i)
#pragma unroll
                for (int j = 0; j < 4; ++j) acc[i][j] += xv[i] * wvv[j];
        }
    }
#pragma unroll
    for (int i = 0; i < 8; ++i) {
        int node = nbase + ng * 8 + i;
        if (node < N_NODES) {
            float dv = dinv[node];
            vh4 o;
            o.x = (_Float16)(acc[i][0] * dv); o.y = (_Float16)(acc[i][1] * dv);
            o.z = (_Float16)(acc[i][2] * dv); o.w = (_Float16)(acc[i][3] * dv);
            *(vh4*)(out + (size_t)node * 64 + cg * 4) = o;
        }
    }
}

// ---------------------------------------------------------------------------
// CSR gather-aggregation, half-wave edge-split: lanes 0-31 process even edges,
// lanes 32-63 odd edges of the SAME node; each lane loads a uint (2 fp16
// channels 2*hl, 2*hl+1). One wave-load = 2 edge rows (256 B) -> gather
// instructions halve vs the 2B/lane layout. Combine halves via shfl_xor(32).
//   out[v] = dinv[v]*(sum w*h'[r] + h'[v]) + bias
__global__ __launch_bounds__(256) void k_agg(const _Float16* __restrict__ hin,
                                             const unsigned* __restrict__ ebuf2,
                                             const int2* __restrict__ nrange,
                                             const float* __restrict__ dinv,
                                             const float* __restrict__ bias,
                                             _Float16* __restrict__ hout,
                                             float* __restrict__ bn_shard) {
    __shared__ unsigned sme[AGG_CAP];
    __shared__ float sm[4][64], qm[4][64];
    int b = blockIdx.x, t = threadIdx.x;
    int wave = t >> 6, lane = t & 63;
    int half = lane >> 5, hl = lane & 31;
    const unsigned* hinu = (const unsigned*)hin;   // 2 fp16 per uint
    int vbase0 = b * 32;                           // grid is exactly N_NODES/32
    int ebeg = nrange[vbase0].x;
    int eend = nrange[vbase0 + 31].y;
    int n = eend - ebeg;
    bool fit = (n <= AGG_CAP);
    if (fit) {
        for (int i = t; i < n; i += 256) sme[i] = nt_u(ebuf2 + ebeg + i);
    }
    __syncthreads();

    float s0 = 0.f, q0 = 0.f, s1 = 0.f, q1 = 0.f;
    float bl0 = bias[2 * hl], bl1 = bias[2 * hl + 1];
    int vbase = vbase0 + wave * 8;
    for (int vi = 0; vi < 8; ++vi) {
        int v = vbase + vi;
        int2 be = nrange[v];
        int end = be.y;
        float a0 = 0.f, a1 = 0.f;
        int j = be.x + half;                       // this half's edge stream
        if (fit) {
            int jl = j - ebeg;
            // 8 pairs (16 edges) per iteration, gathers batched before fma
            for (; j + 16 <= end; j += 16, jl += 16) {
                float fw[8];
                unsigned hv[8];
#pragma unroll
                for (int u = 0; u < 8; ++u) {
                    unsigned e = sme[jl + 2 * u];
                    fw[u] = unpack_w(e);
                    hv[u] = hinu[((size_t)(e >> 15) << 5) + hl];
                }
#pragma unroll
                for (int u = 0; u < 8; ++u) {
                    a0 = fmaf(fw[u], f16lo(hv[u]), a0);
                    a1 = fmaf(fw[u], f16hi(hv[u]), a1);
                }
            }
            for (; j < end; j += 2, jl += 2) {
                unsigned e = sme[jl];
                float fw = unpack_w(e);
                unsigned hv = hinu[((size_t)(e >> 15) << 5) + hl];
                a0 = fmaf(fw, f16lo(hv), a0);
                a1 = fmaf(fw, f16hi(hv), a1);
            }
        } else {
            for (; j + 16 <= end; j += 16) {
                float fw[8];
                unsigned hv[8];
#pragma unroll
                for (int u = 0; u < 8; ++u) {
                    unsigned e = nt_u(ebuf2 + j + 2 * u);
                    fw[u] = unpack_w(e);
                    hv[u] = hinu[((size_t)(e >> 15) << 5) + hl];
                }
#pragma unroll
                for (int u = 0; u < 8; ++u) {
                    a0 = fmaf(fw[u], f16lo(hv[u]), a0);
                    a1 = fmaf(fw[u], f16hi(hv[u]), a1);
                }
            }
            for (; j < end; j += 2) {
                unsigned e = nt_u(ebuf2 + j);
                float fw = unpack_w(e);
                unsigned hv = hinu[((size_t)(e >> 15) << 5) + hl];
                a0 = fmaf(fw, f16lo(hv), a0);
                a1 = fmaf(fw, f16hi(hv), a1);
            }
        }
        // combine the two halves (lanes l and l+32 hold the same channels)
        a0 += __shfl_xor(a0, 32);
        a1 += __shfl_xor(a1, 32);
        // self-loop + dinv + bias
        unsigned hv = hinu[((size_t)v << 5) + hl];
        float dv = dinv[v];
        a0 = fmaf(dv, a0 + f16lo(hv), bl0);
        a1 = fmaf(dv, a1 + f16hi(hv), bl1);
        if (half == 0) {
            ((unsigned*)hout)[((size_t)v << 5) + hl] = packh2(a0, a1);
            s0 += a0; q0 += a0 * a0;
            s1 += a1; q1 += a1 * a1;
        }
    }
    if (half == 0) {
        sm[wave][2 * hl] = s0; sm[wave][2 * hl + 1] = s1;
        qm[wave][2 * hl] = q0; qm[wave][2 * hl + 1] = q1;
    }
    __syncthreads();
    if (wave == 0) {
        float ts = sm[0][lane] + sm[1][lane] + sm[2][lane] + sm[3][lane];
        float tq = qm[0][lane] + qm[1][lane] + qm[2][lane] + qm[3][lane];
        float* shard = bn_shard + (blockIdx.x & (NSHARD - 1)) * 128;
        atomicAdd(&shard[lane], ts);
        atomicAdd(&shard[64 + lane], tq);
    }
}

// reduce BN shards -> scale/shift; re-zero shards for the next layer
__global__ void k_bn_final(float* __restrict__ bn_shard, const float* __restrict__ gamma,
                           const float* __restrict__ beta, float* __restrict__ scale,
                           float* __restrict__ shift) {
    int t = threadIdx.x;
    if (t < 64) {
        float s = 0.f, q = 0.f;
        for (int i = 0; i < NSHARD; ++i) {
            s += bn_shard[i * 128 + t];
            q += bn_shard[i * 128 + 64 + t];
        }
        float mean = s * (1.0f / N_NODES);
        float var = q * (1.0f / N_NODES) - mean * mean;
        float sc = gamma[t] * rsqrtf(var + BN_EPS);
        scale[t] = sc;
        shift[t] = beta[t] - mean * sc;
    }
    __syncthreads();
    for (int i = t; i < NSHARD * 128; i += 256) bn_shard[i] = 0.f;
}

// ---------------------------------------------------------------------------
// pool: 782 blocks x 128 rows, sharded accumulators (blockIdx&15, XCD-local)
__global__ __launch_bounds__(256) void k_pool(const _Float16* __restrict__ a2,
                                              const float* __restrict__ scale,
                                              const float* __restrict__ shift,
                                              const int* __restrict__ batch,
                                              float* __restrict__ pooled_sh,
                                              float* __restrict__ pcnt_sh) {
    int b = blockIdx.x, t = threadIdx.x;
    int c = t & 63;
    int rg = t >> 6;
    int base = b * BUCK_SZ;
    float sc = scale[c], sh = shift[c];
    float* pool_s = pooled_sh + (size_t)(b & (NSHARD - 1)) * (N_GRAPHS * 64);
    float* pcnt_s = pcnt_sh + (size_t)(b & (NSHARD - 1)) * N_GRAPHS;
    int gcur = -1;
    float acc = 0.f, cacc = 0.f;
    for (int i = rg; i < BUCK_SZ; i += 4) {
        int v = base + i;
        if (v >= N_NODES) break;
        int g = batch[v];
        if (g != gcur) {
            if (gcur >= 0) {
                atomicAdd(&pool_s[gcur * 64 + c], acc);
                if (c == 0) atomicAdd(&pcnt_s[gcur], cacc);
            }
            gcur = g;
            acc = 0.f;
            cacc = 0.f;
        }
        float h = fmaxf(sc * (float)a2[(size_t)v * 64 + c] + sh, 0.f);
        acc += h;
        cacc += 1.f;
    }
    if (gcur >= 0) {
        atomicAdd(&pool_s[gcur * 64 + c], acc);
        if (c == 0) atomicAdd(&pcnt_s[gcur], cacc);
    }
}

__global__ void k_out(const float* __restrict__ pooled_sh,
                      const float* __restrict__ pcnt_sh,
                      const float* __restrict__ Wout, const float* __restrict__ bout,
                      float* __restrict__ out) {
    int g = threadIdx.x;
    if (g < N_GRAPHS) {
        float cnt = 0.f;
        for (int s = 0; s < NSHARD; ++s) cnt += pcnt_sh[s * N_GRAPHS + g];
        cnt = fmaxf(cnt, 1.0f);
        float sum = 0.f;
        for (int c = 0; c < 64; ++c) {
            float p = 0.f;
            for (int s = 0; s < NSHARD; ++s)
                p += pooled_sh[(size_t)s * N_GRAPHS * 64 + g * 64 + c];
            sum += p * Wout[c];
        }
        out[g] = sum / cnt + bout[0];
    }
}

// ---------------------------------------------------------------------------
extern "C" void kernel_launch(void* const* d_in, const int* in_sizes, int n_in,
                              void* d_out, int out_size, void* d_ws, size_t ws_size,
                              hipStream_t stream) {
    const float* x    = (const float*)d_in[0];
    const int*   ei   = (const int*)d_in[1];
    const float* ew   = (const float*)d_in[2];
    const int*   batch= (const int*)d_in[3];
    const float* W1   = (const float*)d_in[4];
    const float* b1   = (const float*)d_in[5];
    const float* W2   = (const float*)d_in[6];
    const float* b2   = (const float*)d_in[7];
    const float* g1   = (const float*)d_in[8];
    const float* be1  = (const float*)d_in[9];
    const float* g2   = (const float*)d_in[10];
    const float* be2  = (const float*)d_in[11];
    const float* Wout = (const float*)d_in[12];
    const float* bout = (const float*)d_in[13];
    float* out = (float*)d_out;

    char* w = (char*)d_ws;
    size_t o = 0;
    auto alloc = [&](size_t bytes) -> void* {
        void* p = w + o;
        o = (o + bytes + 255) & ~(size_t)255;
        return p;
    };
    int*   cur     = (int*)alloc(NCNT * 4);
    int2*  nrange  = (int2*)alloc((size_t)N_NODES * 8);
    float* dinv    = (float*)alloc(N_NODES * 4);
    float* bnshard = (float*)alloc(NSHARD * 128 * 4);
    float* scale1  = (float*)alloc(64 * 4);
    float* shift1  = (float*)alloc(64 * 4);
    float* scale2  = (float*)alloc(64 * 4);
    float* shift2  = (float*)alloc(64 * 4);
    float* pooled  = (float*)alloc(NSHARD * N_GRAPHS * 64 * 4);
    float* pcnt    = (float*)alloc(NSHARD * N_GRAPHS * 4);
    unsigned* ebuf2 = (unsigned*)alloc((size_t)NBUCK * BCAP * 4);  // 14.4 MB
    // 38.4 MB region double-use: ebuf (slotted binning scratch, dead after
    // k_sortnorm), then two fp16 node buffers HA/HB (12.8 MB each).
    uint2* ebuf    = (uint2*)alloc((size_t)NCNT * SLOT_CAP * 8);   // 38.4 MB
    _Float16* bufHA = (_Float16*)ebuf;
    _Float16* bufHB = bufHA + (size_t)N_NODES * 64;
    if (o > ws_size) return;

    (void)hipMemsetAsync(bnshard, 0, NSHARD * 128 * 4, stream);
    (void)hipMemsetAsync(pooled, 0, NSHARD * N_GRAPHS * 64 * 4, stream);
    (void)hipMemsetAsync(pcnt, 0, NSHARD * N_GRAPHS * 4, stream);

    k_init<<<(NCNT + 255) / 256, 256, 0, stream>>>(cur);
    k_bin<<<BIN_BLOCKS, 512, 0, stream>>>(ei, ew, cur, ebuf);
    k_sortnorm<<<NBUCK, 512, 0, stream>>>(ebuf, cur, dinv, ebuf2, nrange);

    // layer 1: x (f32) -> h1' = dinv*(x@W1) (fp16) -> a1 (fp16) + BN1 stats
    k_gemm<128, false><<<(N_NODES + 127) / 128, 256, 0, stream>>>(x, W1, nullptr, nullptr, dinv, bufHA);
    k_agg<<<N_NODES / 32, 256, 0, stream>>>(bufHA, ebuf2, nrange, dinv, b1, bufHB, bnshard);
    k_bn_final<<<1, 256, 0, stream>>>(bnshard, g1, be1, scale1, shift1);

    // layer 2: a1 (fp16, fused BN+ReLU) -> h2' (fp16) -> a2 (fp16) + BN2 stats
    k_gemm<64, true><<<(N_NODES + 127) / 128, 256, 0, stream>>>(bufHB, W2, scale1, shift1, dinv, bufHA);
    k_agg<<<N_NODES / 32, 256, 0, stream>>>(bufHA, ebuf2, nrange, dinv, b2, bufHB, bnshard);
    k_bn_final<<<1, 256, 0, stream>>>(bnshard, g2, be2, scale2, shift2);

    // pool (fused BN2+ReLU, sharded accumulators) + output
    k_pool<<<NBUCK, 256, 0, stream>>>(bufHB, scale2, shift2, batch, pooled, pcnt);
    k_out<<<1, 64, 0, stream>>>(pooled, pcnt, Wout, bout, out);
}

// Round 19
// 310.579 us; speedup vs baseline: 1.2884x; 1.1246x over previous
//
#include <hip/hip_runtime.h>
#include <stdint.h>

#define N_NODES 100000
#define N_EDGES 3200000
#define IN_DIM 128
#define HID 64
#define N_GRAPHS 64
#define BN_EPS 1e-5f
#define NSHARD 16
#define BUCK_SH 7
#define BUCK_SZ 128
#define NBUCK ((N_NODES + BUCK_SZ - 1) / BUCK_SZ)   // 782
#define NCNT (NBUCK * 8)                             // 6256
#define BINB_EDGES 4096                              // edges per binning block
#define BIN_BLOCKS ((N_EDGES + BINB_EDGES - 1) / BINB_EDGES)  // 782
#define SLOT_CAP 768                                 // per-(stream,bucket) ebuf slot
#define BCAP 4608                                    // per-bucket ebuf2 region
#define SORT_CAP (8 * SLOT_CAP)                      // 6144
#define AGG_CAP 2048                                 // agg block edge stage (mean 1024)

// __builtin_nontemporal_load needs native (ext_vector) types, not HIP structs.
typedef float vf4 __attribute__((ext_vector_type(4)));
typedef int   vi4 __attribute__((ext_vector_type(4)));
typedef unsigned vu2 __attribute__((ext_vector_type(2)));
typedef _Float16 vh4 __attribute__((ext_vector_type(4)));
typedef _Float16 vh8 __attribute__((ext_vector_type(8)));

__device__ __forceinline__ float4 nt_f4(const float* p) {
    vf4 v = __builtin_nontemporal_load((const vf4*)p);
    return make_float4(v.x, v.y, v.z, v.w);
}
__device__ __forceinline__ int4 nt_i4(const int* p) {
    vi4 v = __builtin_nontemporal_load((const vi4*)p);
    return make_int4(v.x, v.y, v.z, v.w);
}
__device__ __forceinline__ uint2 nt_u2(const uint2* p) {
    vu2 v = __builtin_nontemporal_load((const vu2*)p);
    return make_uint2(v.x, v.y);
}
__device__ __forceinline__ unsigned nt_u(const unsigned* p) {
    return __builtin_nontemporal_load(p);
}
__device__ __forceinline__ vh4 nt_h4(const _Float16* p) {
    return __builtin_nontemporal_load((const vh4*)p);
}

// packed edge: (r << 15) | fp16_bits(w)   [w >= 0 so sign bit free; r < 2^17]
__device__ __forceinline__ unsigned pack_edge(unsigned r, _Float16 w) {
    unsigned short hb = __builtin_bit_cast(unsigned short, w);
    return (r << 15) | (unsigned)hb;
}
__device__ __forceinline__ float unpack_w(unsigned u) {
    return (float)__builtin_bit_cast(_Float16, (unsigned short)(u & 0x7FFFu));
}
__device__ __forceinline__ float f16lo(unsigned u) {
    return (float)__builtin_bit_cast(_Float16, (unsigned short)(u & 0xFFFFu));
}
__device__ __forceinline__ float f16hi(unsigned u) {
    return (float)__builtin_bit_cast(_Float16, (unsigned short)(u >> 16));
}
__device__ __forceinline__ unsigned packh2(float a, float b) {
    unsigned short la = __builtin_bit_cast(unsigned short, (_Float16)a);
    unsigned short lb = __builtin_bit_cast(unsigned short, (_Float16)b);
    return (unsigned)la | ((unsigned)lb << 16);
}

// ---------------------------------------------------------------------------
// init per-(stream,bucket) cursors to fixed slot bases (cur[s*NBUCK+j]:
// XCD-local 3.1 KB regions — avoids cross-XCD cursor-line ping-pong)
__global__ void k_init(int* __restrict__ cur) {
    int i = blockIdx.x * blockDim.x + threadIdx.x;
    if (i < NCNT) cur[i] = i * SLOT_CAP;
}

// bin: two NT passes over global, LDS = 782-int histogram, 512 threads.
__global__ __launch_bounds__(512) void k_bin(const int* __restrict__ ei,
                                             const float* __restrict__ ew,
                                             int* __restrict__ cur,
                                             uint2* __restrict__ ebuf) {
    __shared__ int hist[NBUCK];
    int b = blockIdx.x, t = threadIdx.x;
    int s = b & 7;
    int base = b * BINB_EDGES;
    int n = min(BINB_EDGES, N_EDGES - base);
    for (int i = t; i < NBUCK; i += 512) hist[i] = 0;
    __syncthreads();
#pragma unroll
    for (int k = 0; k < 2; ++k) {
        int ch = t + 512 * k;
        if (4 * ch < n) {
            int4 c4 = nt_i4(ei + N_EDGES + base + 4 * ch);
            atomicAdd(&hist[c4.x >> BUCK_SH], 1);
            atomicAdd(&hist[c4.y >> BUCK_SH], 1);
            atomicAdd(&hist[c4.z >> BUCK_SH], 1);
            atomicAdd(&hist[c4.w >> BUCK_SH], 1);
        }
    }
    __syncthreads();
    for (int j = t; j < NBUCK; j += 512) {
        int h = hist[j];
        if (h > 0) hist[j] = atomicAdd(&cur[s * NBUCK + j], h);
    }
    __syncthreads();
#pragma unroll
    for (int k = 0; k < 2; ++k) {
        int ch = t + 512 * k;
        if (4 * ch < n) {
            int4 r4 = nt_i4(ei + base + 4 * ch);
            int4 c4 = nt_i4(ei + N_EDGES + base + 4 * ch);
            float4 w4 = nt_f4(ew + base + 4 * ch);
            int rr[4] = {r4.x, r4.y, r4.z, r4.w};
            int cc[4] = {c4.x, c4.y, c4.z, c4.w};
            float ww[4] = {w4.x, w4.y, w4.z, w4.w};
            int pos[4];
#pragma unroll
            for (int u = 0; u < 4; ++u)
                pos[u] = atomicAdd(&hist[cc[u] >> BUCK_SH], 1);
#pragma unroll
            for (int u = 0; u < 4; ++u)
                ebuf[pos[u]] = make_uint2(
                    (unsigned)(rr[u] | ((cc[u] & (BUCK_SZ - 1)) << 17)),
                    __float_as_uint(ww[u]));
        }
    }
}

// ---------------------------------------------------------------------------
// fused prep, 512 threads: per bucket, stage 8 slots, weighted degree (full
// precision) -> dinv[c], dest histogram -> per-node ranges, scatter 4-byte
// packed edges {r, fp16(w)}. dinv applied per-node in agg epilogue.
__global__ __launch_bounds__(512) void k_sortnorm(const uint2* __restrict__ ebuf,
                                                  const int* __restrict__ cur,
                                                  float* __restrict__ dinv,
                                                  unsigned* __restrict__ ebuf2,
                                                  int2* __restrict__ nrange) {
    __shared__ unsigned sex[SORT_CAP];   // r | cl<<17
    __shared__ _Float16 sew[SORT_CAP];   // fp16 weight
    __shared__ float sdi[BUCK_SZ];       // degree accum, then dinv
    __shared__ int scnt[BUCK_SZ];
    __shared__ int scur[BUCK_SZ];
    __shared__ int slen[8], soffc[8];
    int b = blockIdx.x, t = threadIdx.x;
    if (t < BUCK_SZ) { sdi[t] = 0.f; scnt[t] = 0; }
    if (t < 8) slen[t] = cur[t * NBUCK + b] - (t * NBUCK + b) * SLOT_CAP;
    __syncthreads();
    if (t == 0) {
        int run = 0;
#pragma unroll
        for (int s = 0; s < 8; ++s) { soffc[s] = run; run += slen[s]; }
    }
    __syncthreads();
    for (int s = 0; s < 8; ++s) {
        int sb = (s * NBUCK + b) * SLOT_CAP;
        int len = slen[s];
        int off = soffc[s];
        for (int i = t; i < len; i += 512) {
            uint2 u = nt_u2(ebuf + sb + i);
            float wf = __uint_as_float(u.y);
            sex[off + i] = u.x;
            sew[off + i] = (_Float16)wf;
            int cl = u.x >> 17;
            atomicAdd(&sdi[cl], wf);
            atomicAdd(&scnt[cl], 1);
        }
    }
    __syncthreads();
    int n = soffc[7] + slen[7];
    if (t < BUCK_SZ) {
        float di = rsqrtf(sdi[t] + 1.0f);   // +1 = self-loop weight
        int node = b * BUCK_SZ + t;
        if (node < N_NODES) dinv[node] = di;
    }
    __syncthreads();
    for (int off = 1; off < BUCK_SZ; off <<= 1) {
        int x = 0;
        if (t < BUCK_SZ && t >= off) x = scnt[t - off];
        __syncthreads();
        if (t < BUCK_SZ) scnt[t] += x;
        __syncthreads();
    }
    if (t < BUCK_SZ) {
        int excl = (t > 0) ? scnt[t - 1] : 0;
        int cnt = scnt[t] - excl;
        scur[t] = b * BCAP + excl;
        int node = b * BUCK_SZ + t;
        if (node < N_NODES) nrange[node] = make_int2(b * BCAP + excl, b * BCAP + excl + cnt);
    }
    __syncthreads();
    for (int i = t; i < n; i += 512) {
        unsigned x = sex[i];
        unsigned r = x & 131071u;
        int cl = x >> 17;
        int p = atomicAdd(&scur[cl], 1);
        ebuf2[p] = pack_edge(r, sew[i]);
    }
}

// ---------------------------------------------------------------------------
// MFMA GEMM: out[n][c] = dinv[n]*(in@W)[n][c], fp16 out, f32 accumulate.
// v_mfma_f32_16x16x32_f16; block = 128 nodes x 64 cols, 4 waves x (2 row-
// tiles x 4 col-tiles). Fragment layouts (CDNA): A: row=lane&15,
// k=(lane>>4)*8+e; B: col=lane&15, same k; C/D: col=lane&15,
// row=(lane>>4)*4+r (m89-verified, dtype-independent).
template <int K, bool BNH>
__global__ __launch_bounds__(256) void k_gemm(const void* __restrict__ in_,
                                              const float* __restrict__ W,
                                              const float* __restrict__ scale,
                                              const float* __restrict__ shift,
                                              const float* __restrict__ dinv,
                                              _Float16* __restrict__ out) {
    constexpr int KT = K / 32;
    __shared__ vh8 sW[KT * 4 * 64];      // B-frags: [kt][ct][lane], 16B/lane
    __shared__ _Float16 sA[128 * 40];    // A tile, row stride 40 (80B: 16B-mult, 2-way banks)
    __shared__ float ssc[64], ssh[64];
    int t = threadIdx.x;
    int lane = t & 63, wave = t >> 6;
    int nbase = blockIdx.x * 128;
    if (BNH && t < 64) { ssc[t] = scale[t]; ssh[t] = shift[t]; }

    // pre-arrange B fragments (one-time; W is tiny and L2-hot)
    for (int eidx = t; eidx < KT * 4 * 64; eidx += 256) {
        int l = eidx & 63, ct = (eidx >> 6) & 3, kt = eidx >> 8;
        int kb = kt * 32 + (l >> 4) * 8;
        int col = ct * 16 + (l & 15);
        vh8 h;
#pragma unroll
        for (int e = 0; e < 8; ++e) h[e] = (_Float16)W[(kb + e) * 64 + col];
        sW[eidx] = h;
    }

    vf4 acc[2][4];
#pragma unroll
    for (int i = 0; i < 2; ++i)
#pragma unroll
        for (int j = 0; j < 4; ++j) acc[i][j] = (vf4){0.f, 0.f, 0.f, 0.f};

    for (int kt = 0; kt < KT; ++kt) {
        __syncthreads();
        // stage 128 nodes x 32 k as fp16 (4 elems per (row,kq) unit)
#pragma unroll
        for (int i = 0; i < 4; ++i) {
            int idx = t + 256 * i;
            int row = idx >> 3, kq = idx & 7;
            int node = nbase + row;
            float vv[4] = {0.f, 0.f, 0.f, 0.f};
            if (node < N_NODES) {
                if (BNH) {
                    vh4 v = nt_h4((const _Float16*)in_ + (size_t)node * K + kt * 32 + kq * 4);
                    vv[0] = (float)v.x; vv[1] = (float)v.y;
                    vv[2] = (float)v.z; vv[3] = (float)v.w;
#pragma unroll
                    for (int u = 0; u < 4; ++u) {
                        int k = kt * 32 + kq * 4 + u;
                        vv[u] = fmaxf(ssc[k] * vv[u] + ssh[k], 0.f);
                    }
                } else {
                    float4 v = nt_f4((const float*)in_ + (size_t)node * K + kt * 32 + kq * 4);
                    vv[0] = v.x; vv[1] = v.y; vv[2] = v.z; vv[3] = v.w;
                }
            }
            vh4 hv;
            hv.x = (_Float16)vv[0]; hv.y = (_Float16)vv[1];
            hv.z = (_Float16)vv[2]; hv.w = (_Float16)vv[3];
            *(vh4*)(sA + row * 40 + kq * 4) = hv;
        }
        __syncthreads();
        // fragments + MFMA
        vh8 a0 = *(const vh8*)(sA + (wave * 32 + (lane & 15)) * 40 + (lane >> 4) * 8);
        vh8 a1 = *(const vh8*)(sA + (wave * 32 + 16 + (lane & 15)) * 40 + (lane >> 4) * 8);
#pragma unroll
        for (int ct = 0; ct < 4; ++ct) {
            vh8 bfr = sW[(kt * 4 + ct) * 64 + lane];
            acc[0][ct] = __builtin_amdgcn_mfma_f32_16x16x32_f16(a0, bfr, acc[0][ct], 0, 0, 0);
            acc[1][ct] = __builtin_amdgcn_mfma_f32_16x16x32_f16(a1, bfr, acc[1][ct], 0, 0, 0);
        }
    }
    // epilogue: D[row=(lane>>4)*4+r][col=lane&15]; scale by dinv, fp16 store
    int colb = lane & 15, rq = lane >> 4;
#pragma unroll
    for (int rti = 0; rti < 2; ++rti) {
#pragma unroll
        for (int r = 0; r < 4; ++r) {
            int node = nbase + wave * 32 + rti * 16 + rq * 4 + r;
            if (node < N_NODES) {
                float dv = dinv[node];
#pragma unroll
                for (int ct = 0; ct < 4; ++ct)
                    out[(size_t)node * 64 + ct * 16 + colb] =
                        (_Float16)(acc[rti][ct][r] * dv);
            }
        }
    }
}

// ---------------------------------------------------------------------------
// CSR gather-aggregation, half-wave edge-split (converged at fabric rate):
//   out[v] = dinv[v]*(sum w*h'[r] + h'[v]) + bias
__global__ __launch_bounds__(256) void k_agg(const _Float16* __restrict__ hin,
                                             const unsigned* __restrict__ ebuf2,
                                             const int2* __restrict__ nrange,
                                             const float* __restrict__ dinv,
                                             const float* __restrict__ bias,
                                             _Float16* __restrict__ hout,
                                             float* __restrict__ bn_shard) {
    __shared__ unsigned sme[AGG_CAP];
    __shared__ float sm[4][64], qm[4][64];
    int b = blockIdx.x, t = threadIdx.x;
    int wave = t >> 6, lane = t & 63;
    int half = lane >> 5, hl = lane & 31;
    const unsigned* hinu = (const unsigned*)hin;   // 2 fp16 per uint
    int vbase0 = b * 32;                           // grid is exactly N_NODES/32
    int ebeg = nrange[vbase0].x;
    int eend = nrange[vbase0 + 31].y;
    int n = eend - ebeg;
    bool fit = (n <= AGG_CAP);
    if (fit) {
        for (int i = t; i < n; i += 256) sme[i] = nt_u(ebuf2 + ebeg + i);
    }
    __syncthreads();

    float s0 = 0.f, q0 = 0.f, s1 = 0.f, q1 = 0.f;
    float bl0 = bias[2 * hl], bl1 = bias[2 * hl + 1];
    int vbase = vbase0 + wave * 8;
    for (int vi = 0; vi < 8; ++vi) {
        int v = vbase + vi;
        int2 be = nrange[v];
        int end = be.y;
        float a0 = 0.f, a1 = 0.f;
        int j = be.x + half;                       // this half's edge stream
        if (fit) {
            int jl = j - ebeg;
            for (; j + 16 <= end; j += 16, jl += 16) {
                float fw[8];
                unsigned hv[8];
#pragma unroll
                for (int u = 0; u < 8; ++u) {
                    unsigned e = sme[jl + 2 * u];
                    fw[u] = unpack_w(e);
                    hv[u] = hinu[((size_t)(e >> 15) << 5) + hl];
                }
#pragma unroll
                for (int u = 0; u < 8; ++u) {
                    a0 = fmaf(fw[u], f16lo(hv[u]), a0);
                    a1 = fmaf(fw[u], f16hi(hv[u]), a1);
                }
            }
            for (; j < end; j += 2, jl += 2) {
                unsigned e = sme[jl];
                float fw = unpack_w(e);
                unsigned hv = hinu[((size_t)(e >> 15) << 5) + hl];
                a0 = fmaf(fw, f16lo(hv), a0);
                a1 = fmaf(fw, f16hi(hv), a1);
            }
        } else {
            for (; j + 16 <= end; j += 16) {
                float fw[8];
                unsigned hv[8];
#pragma unroll
                for (int u = 0; u < 8; ++u) {
                    unsigned e = nt_u(ebuf2 + j + 2 * u);
                    fw[u] = unpack_w(e);
                    hv[u] = hinu[((size_t)(e >> 15) << 5) + hl];
                }
#pragma unroll
                for (int u = 0; u < 8; ++u) {
                    a0 = fmaf(fw[u], f16lo(hv[u]), a0);
                    a1 = fmaf(fw[u], f16hi(hv[u]), a1);
                }
            }
            for (; j < end; j += 2) {
                unsigned e = nt_u(ebuf2 + j);
                float fw = unpack_w(e);
                unsigned hv = hinu[((size_t)(e >> 15) << 5) + hl];
                a0 = fmaf(fw, f16lo(hv), a0);
                a1 = fmaf(fw, f16hi(hv), a1);
            }
        }
        a0 += __shfl_xor(a0, 32);
        a1 += __shfl_xor(a1, 32);
        unsigned hv = hinu[((size_t)v << 5) + hl];
        float dv = dinv[v];
        a0 = fmaf(dv, a0 + f16lo(hv), bl0);
        a1 = fmaf(dv, a1 + f16hi(hv), bl1);
        if (half == 0) {
            ((unsigned*)hout)[((size_t)v << 5) + hl] = packh2(a0, a1);
            s0 += a0; q0 += a0 * a0;
            s1 += a1; q1 += a1 * a1;
        }
    }
    if (half == 0) {
        sm[wave][2 * hl] = s0; sm[wave][2 * hl + 1] = s1;
        qm[wave][2 * hl] = q0; qm[wave][2 * hl + 1] = q1;
    }
    __syncthreads();
    if (wave == 0) {
        float ts = sm[0][lane] + sm[1][lane] + sm[2][lane] + sm[3][lane];
        float tq = qm[0][lane] + qm[1][lane] + qm[2][lane] + qm[3][lane];
        float* shard = bn_shard + (blockIdx.x & (NSHARD - 1)) * 128;
        atomicAdd(&shard[lane], ts);
        atomicAdd(&shard[64 + lane], tq);
    }
}

// reduce BN shards -> scale/shift; re-zero shards for the next layer
__global__ void k_bn_final(float* __restrict__ bn_shard, const float* __restrict__ gamma,
                           const float* __restrict__ beta, float* __restrict__ scale,
                           float* __restrict__ shift) {
    int t = threadIdx.x;
    if (t < 64) {
        float s = 0.f, q = 0.f;
        for (int i = 0; i < NSHARD; ++i) {
            s += bn_shard[i * 128 + t];
            q += bn_shard[i * 128 + 64 + t];
        }
        float mean = s * (1.0f / N_NODES);
        float var = q * (1.0f / N_NODES) - mean * mean;
        float sc = gamma[t] * rsqrtf(var + BN_EPS);
        scale[t] = sc;
        shift[t] = beta[t] - mean * sc;
    }
    __syncthreads();
    for (int i = t; i < NSHARD * 128; i += 256) bn_shard[i] = 0.f;
}

// ---------------------------------------------------------------------------
// pool: 782 blocks x 128 rows, sharded accumulators (blockIdx&15, XCD-local)
__global__ __launch_bounds__(256) void k_pool(const _Float16* __restrict__ a2,
                                              const float* __restrict__ scale,
                                              const float* __restrict__ shift,
                                              const int* __restrict__ batch,
                                              float* __restrict__ pooled_sh,
                                              float* __restrict__ pcnt_sh) {
    int b = blockIdx.x, t = threadIdx.x;
    int c = t & 63;
    int rg = t >> 6;
    int base = b * BUCK_SZ;
    float sc = scale[c], sh = shift[c];
    float* pool_s = pooled_sh + (size_t)(b & (NSHARD - 1)) * (N_GRAPHS * 64);
    float* pcnt_s = pcnt_sh + (size_t)(b & (NSHARD - 1)) * N_GRAPHS;
    int gcur = -1;
    float acc = 0.f, cacc = 0.f;
    for (int i = rg; i < BUCK_SZ; i += 4) {
        int v = base + i;
        if (v >= N_NODES) break;
        int g = batch[v];
        if (g != gcur) {
            if (gcur >= 0) {
                atomicAdd(&pool_s[gcur * 64 + c], acc);
                if (c == 0) atomicAdd(&pcnt_s[gcur], cacc);
            }
            gcur = g;
            acc = 0.f;
            cacc = 0.f;
        }
        float h = fmaxf(sc * (float)a2[(size_t)v * 64 + c] + sh, 0.f);
        acc += h;
        cacc += 1.f;
    }
    if (gcur >= 0) {
        atomicAdd(&pool_s[gcur * 64 + c], acc);
        if (c == 0) atomicAdd(&pcnt_s[gcur], cacc);
    }
}

__global__ void k_out(const float* __restrict__ pooled_sh,
                      const float* __restrict__ pcnt_sh,
                      const float* __restrict__ Wout, const float* __restrict__ bout,
                      float* __restrict__ out) {
    int g = threadIdx.x;
    if (g < N_GRAPHS) {
        float cnt = 0.f;
        for (int s = 0; s < NSHARD; ++s) cnt += pcnt_sh[s * N_GRAPHS + g];
        cnt = fmaxf(cnt, 1.0f);
        float sum = 0.f;
        for (int c = 0; c < 64; ++c) {
            float p = 0.f;
            for (int s = 0; s < NSHARD; ++s)
                p += pooled_sh[(size_t)s * N_GRAPHS * 64 + g * 64 + c];
            sum += p * Wout[c];
        }
        out[g] = sum / cnt + bout[0];
    }
}

// ---------------------------------------------------------------------------
extern "C" void kernel_launch(void* const* d_in, const int* in_sizes, int n_in,
                              void* d_out, int out_size, void* d_ws, size_t ws_size,
                              hipStream_t stream) {
    const float* x    = (const float*)d_in[0];
    const int*   ei   = (const int*)d_in[1];
    const float* ew   = (const float*)d_in[2];
    const int*   batch= (const int*)d_in[3];
    const float* W1   = (const float*)d_in[4];
    const float* b1   = (const float*)d_in[5];
    const float* W2   = (const float*)d_in[6];
    const float* b2   = (const float*)d_in[7];
    const float* g1   = (const float*)d_in[8];
    const float* be1  = (const float*)d_in[9];
    const float* g2   = (const float*)d_in[10];
    const float* be2  = (const float*)d_in[11];
    const float* Wout = (const float*)d_in[12];
    const float* bout = (const float*)d_in[13];
    float* out = (float*)d_out;

    char* w = (char*)d_ws;
    size_t o = 0;
    auto alloc = [&](size_t bytes) -> void* {
        void* p = w + o;
        o = (o + bytes + 255) & ~(size_t)255;
        return p;
    };
    int*   cur     = (int*)alloc(NCNT * 4);
    int2*  nrange  = (int2*)alloc((size_t)N_NODES * 8);
    float* dinv    = (float*)alloc(N_NODES * 4);
    float* bnshard = (float*)alloc(NSHARD * 128 * 4);
    float* scale1  = (float*)alloc(64 * 4);
    float* shift1  = (float*)alloc(64 * 4);
    float* scale2  = (float*)alloc(64 * 4);
    float* shift2  = (float*)alloc(64 * 4);
    float* pooled  = (float*)alloc(NSHARD * N_GRAPHS * 64 * 4);
    float* pcnt    = (float*)alloc(NSHARD * N_GRAPHS * 4);
    unsigned* ebuf2 = (unsigned*)alloc((size_t)NBUCK * BCAP * 4);  // 14.4 MB
    // 38.4 MB region double-use: ebuf (slotted binning scratch, dead after
    // k_sortnorm), then two fp16 node buffers HA/HB (12.8 MB each).
    uint2* ebuf    = (uint2*)alloc((size_t)NCNT * SLOT_CAP * 8);   // 38.4 MB
    _Float16* bufHA = (_Float16*)ebuf;
    _Float16* bufHB = bufHA + (size_t)N_NODES * 64;
    if (o > ws_size) return;

    (void)hipMemsetAsync(bnshard, 0, NSHARD * 128 * 4, stream);
    (void)hipMemsetAsync(pooled, 0, NSHARD * N_GRAPHS * 64 * 4, stream);
    (void)hipMemsetAsync(pcnt, 0, NSHARD * N_GRAPHS * 4, stream);

    k_init<<<(NCNT + 255) / 256, 256, 0, stream>>>(cur);
    k_bin<<<BIN_BLOCKS, 512, 0, stream>>>(ei, ew, cur, ebuf);
    k_sortnorm<<<NBUCK, 512, 0, stream>>>(ebuf, cur, dinv, ebuf2, nrange);

    // layer 1: x (f32) -> h1' = dinv*(x@W1) (fp16, MFMA) -> a1 + BN1 stats
    k_gemm<128, false><<<(N_NODES + 127) / 128, 256, 0, stream>>>(x, W1, nullptr, nullptr, dinv, bufHA);
    k_agg<<<N_NODES / 32, 256, 0, stream>>>(bufHA, ebuf2, nrange, dinv, b1, bufHB, bnshard);
    k_bn_final<<<1, 256, 0, stream>>>(bnshard, g1, be1, scale1, shift1);

    // layer 2: a1 (fp16, fused BN+ReLU) -> h2' (fp16, MFMA) -> a2 + BN2 stats
    k_gemm<64, true><<<(N_NODES + 127) / 128, 256, 0, stream>>>(bufHB, W2, scale1, shift1, dinv, bufHA);
    k_agg<<<N_NODES / 32, 256, 0, stream>>>(bufHA, ebuf2, nrange, dinv, b2, bufHB, bnshard);
    k_bn_final<<<1, 256, 0, stream>>>(bnshard, g2, be2, scale2, shift2);

    // pool (fused BN2+ReLU, sharded accumulators) + output
    k_pool<<<NBUCK, 256, 0, stream>>>(bufHB, scale2, shift2, batch, pooled, pcnt);
    k_out<<<1, 64, 0, stream>>>(pooled, pcnt, Wout, bout, out);
}

// Round 20
// 301.075 us; speedup vs baseline: 1.3291x; 1.0316x over previous
//
#include <hip/hip_runtime.h>
#include <stdint.h>

#define N_NODES 100000
#define N_EDGES 3200000
#define IN_DIM 128
#define HID 64
#define N_GRAPHS 64
#define BN_EPS 1e-5f
#define NSHARD 16
#define BUCK_SH 7
#define BUCK_SZ 128
#define NBUCK ((N_NODES + BUCK_SZ - 1) / BUCK_SZ)   // 782
#define NCNT (NBUCK * 8)                             // 6256
#define BINB_EDGES 4096                              // edges per binning block
#define BIN_BLOCKS ((N_EDGES + BINB_EDGES - 1) / BINB_EDGES)  // 782
#define SLOT_CAP 768                                 // per-(stream,bucket) ebuf slot
#define BCAP 4608                                    // per-bucket ebuf2 region
#define SORT_CAP (8 * SLOT_CAP)                      // 6144
#define AGG_CAP 2048                                 // agg block edge stage (mean 1024)

// __builtin_nontemporal_load needs native (ext_vector) types, not HIP structs.
typedef float vf4 __attribute__((ext_vector_type(4)));
typedef int   vi4 __attribute__((ext_vector_type(4)));
typedef unsigned vu2 __attribute__((ext_vector_type(2)));
typedef _Float16 vh4 __attribute__((ext_vector_type(4)));
typedef _Float16 vh8 __attribute__((ext_vector_type(8)));

__device__ __forceinline__ float4 nt_f4(const float* p) {
    vf4 v = __builtin_nontemporal_load((const vf4*)p);
    return make_float4(v.x, v.y, v.z, v.w);
}
__device__ __forceinline__ int4 nt_i4(const int* p) {
    vi4 v = __builtin_nontemporal_load((const vi4*)p);
    return make_int4(v.x, v.y, v.z, v.w);
}
__device__ __forceinline__ uint2 nt_u2(const uint2* p) {
    vu2 v = __builtin_nontemporal_load((const vu2*)p);
    return make_uint2(v.x, v.y);
}
__device__ __forceinline__ unsigned nt_u(const unsigned* p) {
    return __builtin_nontemporal_load(p);
}
__device__ __forceinline__ vh4 nt_h4(const _Float16* p) {
    return __builtin_nontemporal_load((const vh4*)p);
}

// packed edge: (r << 15) | fp16_bits(w)   [w >= 0 so sign bit free; r < 2^17]
__device__ __forceinline__ unsigned pack_edge(unsigned r, _Float16 w) {
    unsigned short hb = __builtin_bit_cast(unsigned short, w);
    return (r << 15) | (unsigned)hb;
}
__device__ __forceinline__ float unpack_w(unsigned u) {
    return (float)__builtin_bit_cast(_Float16, (unsigned short)(u & 0x7FFFu));
}
__device__ __forceinline__ float f16lo(unsigned u) {
    return (float)__builtin_bit_cast(_Float16, (unsigned short)(u & 0xFFFFu));
}
__device__ __forceinline__ float f16hi(unsigned u) {
    return (float)__builtin_bit_cast(_Float16, (unsigned short)(u >> 16));
}
__device__ __forceinline__ unsigned packh2(float a, float b) {
    unsigned short la = __builtin_bit_cast(unsigned short, (_Float16)a);
    unsigned short lb = __builtin_bit_cast(unsigned short, (_Float16)b);
    return (unsigned)la | ((unsigned)lb << 16);
}

// ---------------------------------------------------------------------------
// init: cursors to slot bases + zero both BN shard buffers, pooled, pcnt
// (replaces 1 kernel + 4 hipMemsetAsync dispatches). 256 blocks x 256 thr.
__global__ void k_init(int* __restrict__ cur, float* __restrict__ bnshardA,
                       float* __restrict__ bnshardB, float* __restrict__ pooled,
                       float* __restrict__ pcnt) {
    int i = blockIdx.x * blockDim.x + threadIdx.x;
    int stride = gridDim.x * blockDim.x;
    for (int j = i; j < NCNT; j += stride) cur[j] = j * SLOT_CAP;
    for (int j = i; j < NSHARD * 128; j += stride) {
        bnshardA[j] = 0.f;
        bnshardB[j] = 0.f;
    }
    for (int j = i; j < NSHARD * N_GRAPHS * 64; j += stride) pooled[j] = 0.f;
    for (int j = i; j < NSHARD * N_GRAPHS; j += stride) pcnt[j] = 0.f;
}

// bin: two NT passes over global, LDS = 782-int histogram, 512 threads.
// cur[s*NBUCK+j] layout keeps reserve atomics XCD-local.
__global__ __launch_bounds__(512) void k_bin(const int* __restrict__ ei,
                                             const float* __restrict__ ew,
                                             int* __restrict__ cur,
                                             uint2* __restrict__ ebuf) {
    __shared__ int hist[NBUCK];
    int b = blockIdx.x, t = threadIdx.x;
    int s = b & 7;
    int base = b * BINB_EDGES;
    int n = min(BINB_EDGES, N_EDGES - base);
    for (int i = t; i < NBUCK; i += 512) hist[i] = 0;
    __syncthreads();
#pragma unroll
    for (int k = 0; k < 2; ++k) {
        int ch = t + 512 * k;
        if (4 * ch < n) {
            int4 c4 = nt_i4(ei + N_EDGES + base + 4 * ch);
            atomicAdd(&hist[c4.x >> BUCK_SH], 1);
            atomicAdd(&hist[c4.y >> BUCK_SH], 1);
            atomicAdd(&hist[c4.z >> BUCK_SH], 1);
            atomicAdd(&hist[c4.w >> BUCK_SH], 1);
        }
    }
    __syncthreads();
    for (int j = t; j < NBUCK; j += 512) {
        int h = hist[j];
        if (h > 0) hist[j] = atomicAdd(&cur[s * NBUCK + j], h);
    }
    __syncthreads();
#pragma unroll
    for (int k = 0; k < 2; ++k) {
        int ch = t + 512 * k;
        if (4 * ch < n) {
            int4 r4 = nt_i4(ei + base + 4 * ch);
            int4 c4 = nt_i4(ei + N_EDGES + base + 4 * ch);
            float4 w4 = nt_f4(ew + base + 4 * ch);
            int rr[4] = {r4.x, r4.y, r4.z, r4.w};
            int cc[4] = {c4.x, c4.y, c4.z, c4.w};
            float ww[4] = {w4.x, w4.y, w4.z, w4.w};
            int pos[4];
#pragma unroll
            for (int u = 0; u < 4; ++u)
                pos[u] = atomicAdd(&hist[cc[u] >> BUCK_SH], 1);
#pragma unroll
            for (int u = 0; u < 4; ++u)
                ebuf[pos[u]] = make_uint2(
                    (unsigned)(rr[u] | ((cc[u] & (BUCK_SZ - 1)) << 17)),
                    __float_as_uint(ww[u]));
        }
    }
}

// ---------------------------------------------------------------------------
// fused prep, 512 threads: per bucket, stage 8 slots, weighted degree (full
// precision) -> dinv[c], dest histogram -> per-node ranges, scatter 4-byte
// packed edges {r, fp16(w)}. dinv applied per-node in agg epilogue.
__global__ __launch_bounds__(512) void k_sortnorm(const uint2* __restrict__ ebuf,
                                                  const int* __restrict__ cur,
                                                  float* __restrict__ dinv,
                                                  unsigned* __restrict__ ebuf2,
                                                  int2* __restrict__ nrange) {
    __shared__ unsigned sex[SORT_CAP];   // r | cl<<17
    __shared__ _Float16 sew[SORT_CAP];   // fp16 weight
    __shared__ float sdi[BUCK_SZ];       // degree accum, then dinv
    __shared__ int scnt[BUCK_SZ];
    __shared__ int scur[BUCK_SZ];
    __shared__ int slen[8], soffc[8];
    int b = blockIdx.x, t = threadIdx.x;
    if (t < BUCK_SZ) { sdi[t] = 0.f; scnt[t] = 0; }
    if (t < 8) slen[t] = cur[t * NBUCK + b] - (t * NBUCK + b) * SLOT_CAP;
    __syncthreads();
    if (t == 0) {
        int run = 0;
#pragma unroll
        for (int s = 0; s < 8; ++s) { soffc[s] = run; run += slen[s]; }
    }
    __syncthreads();
    for (int s = 0; s < 8; ++s) {
        int sb = (s * NBUCK + b) * SLOT_CAP;
        int len = slen[s];
        int off = soffc[s];
        for (int i = t; i < len; i += 512) {
            uint2 u = nt_u2(ebuf + sb + i);
            float wf = __uint_as_float(u.y);
            sex[off + i] = u.x;
            sew[off + i] = (_Float16)wf;
            int cl = u.x >> 17;
            atomicAdd(&sdi[cl], wf);
            atomicAdd(&scnt[cl], 1);
        }
    }
    __syncthreads();
    int n = soffc[7] + slen[7];
    if (t < BUCK_SZ) {
        float di = rsqrtf(sdi[t] + 1.0f);   // +1 = self-loop weight
        int node = b * BUCK_SZ + t;
        if (node < N_NODES) dinv[node] = di;
    }
    __syncthreads();
    for (int off = 1; off < BUCK_SZ; off <<= 1) {
        int x = 0;
        if (t < BUCK_SZ && t >= off) x = scnt[t - off];
        __syncthreads();
        if (t < BUCK_SZ) scnt[t] += x;
        __syncthreads();
    }
    if (t < BUCK_SZ) {
        int excl = (t > 0) ? scnt[t - 1] : 0;
        int cnt = scnt[t] - excl;
        scur[t] = b * BCAP + excl;
        int node = b * BUCK_SZ + t;
        if (node < N_NODES) nrange[node] = make_int2(b * BCAP + excl, b * BCAP + excl + cnt);
    }
    __syncthreads();
    for (int i = t; i < n; i += 512) {
        unsigned x = sex[i];
        unsigned r = x & 131071u;
        int cl = x >> 17;
        int p = atomicAdd(&scur[cl], 1);
        ebuf2[p] = pack_edge(r, sew[i]);
    }
}

// ---------------------------------------------------------------------------
// MFMA GEMM: out[n][c] = dinv[n]*(in@W)[n][c], fp16 out, f32 accumulate.
// BNH: input fp16 with fused BN+ReLU; scale/shift computed INLINE from the
// layer-1 BN shard buffer (replaces the separate k_bn_final launch).
template <int K, bool BNH>
__global__ __launch_bounds__(256) void k_gemm(const void* __restrict__ in_,
                                              const float* __restrict__ W,
                                              const float* __restrict__ bnshard,
                                              const float* __restrict__ gamma,
                                              const float* __restrict__ beta,
                                              const float* __restrict__ dinv,
                                              _Float16* __restrict__ out) {
    constexpr int KT = K / 32;
    __shared__ vh8 sW[KT * 4 * 64];      // B-frags: [kt][ct][lane], 16B/lane
    __shared__ _Float16 sA[128 * 40];    // A tile, row stride 40
    __shared__ float ssc[64], ssh[64];
    int t = threadIdx.x;
    int lane = t & 63, wave = t >> 6;
    int nbase = blockIdx.x * 128;
    if (BNH && t < 64) {
        float s = 0.f, q = 0.f;
#pragma unroll
        for (int i = 0; i < NSHARD; ++i) {
            s += bnshard[i * 128 + t];
            q += bnshard[i * 128 + 64 + t];
        }
        float mean = s * (1.0f / N_NODES);
        float var = q * (1.0f / N_NODES) - mean * mean;
        float sc = gamma[t] * rsqrtf(var + BN_EPS);
        ssc[t] = sc;
        ssh[t] = beta[t] - mean * sc;
    }

    // pre-arrange B fragments (one-time; W is tiny and L2-hot)
    for (int eidx = t; eidx < KT * 4 * 64; eidx += 256) {
        int l = eidx & 63, ct = (eidx >> 6) & 3, kt = eidx >> 8;
        int kb = kt * 32 + (l >> 4) * 8;
        int col = ct * 16 + (l & 15);
        vh8 h;
#pragma unroll
        for (int e = 0; e < 8; ++e) h[e] = (_Float16)W[(kb + e) * 64 + col];
        sW[eidx] = h;
    }

    vf4 acc[2][4];
#pragma unroll
    for (int i = 0; i < 2; ++i)
#pragma unroll
        for (int j = 0; j < 4; ++j) acc[i][j] = (vf4){0.f, 0.f, 0.f, 0.f};

    for (int kt = 0; kt < KT; ++kt) {
        __syncthreads();
#pragma unroll
        for (int i = 0; i < 4; ++i) {
            int idx = t + 256 * i;
            int row = idx >> 3, kq = idx & 7;
            int node = nbase + row;
            float vv[4] = {0.f, 0.f, 0.f, 0.f};
            if (node < N_NODES) {
                if (BNH) {
                    vh4 v = nt_h4((const _Float16*)in_ + (size_t)node * K + kt * 32 + kq * 4);
                    vv[0] = (float)v.x; vv[1] = (float)v.y;
                    vv[2] = (float)v.z; vv[3] = (float)v.w;
#pragma unroll
                    for (int u = 0; u < 4; ++u) {
                        int k = kt * 32 + kq * 4 + u;
                        vv[u] = fmaxf(ssc[k] * vv[u] + ssh[k], 0.f);
                    }
                } else {
                    float4 v = nt_f4((const float*)in_ + (size_t)node * K + kt * 32 + kq * 4);
                    vv[0] = v.x; vv[1] = v.y; vv[2] = v.z; vv[3] = v.w;
                }
            }
            vh4 hv;
            hv.x = (_Float16)vv[0]; hv.y = (_Float16)vv[1];
            hv.z = (_Float16)vv[2]; hv.w = (_Float16)vv[3];
            *(vh4*)(sA + row * 40 + kq * 4) = hv;
        }
        __syncthreads();
        vh8 a0 = *(const vh8*)(sA + (wave * 32 + (lane & 15)) * 40 + (lane >> 4) * 8);
        vh8 a1 = *(const vh8*)(sA + (wave * 32 + 16 + (lane & 15)) * 40 + (lane >> 4) * 8);
#pragma unroll
        for (int ct = 0; ct < 4; ++ct) {
            vh8 bfr = sW[(kt * 4 + ct) * 64 + lane];
            acc[0][ct] = __builtin_amdgcn_mfma_f32_16x16x32_f16(a0, bfr, acc[0][ct], 0, 0, 0);
            acc[1][ct] = __builtin_amdgcn_mfma_f32_16x16x32_f16(a1, bfr, acc[1][ct], 0, 0, 0);
        }
    }
    int colb = lane & 15, rq = lane >> 4;
#pragma unroll
    for (int rti = 0; rti < 2; ++rti) {
#pragma unroll
        for (int r = 0; r < 4; ++r) {
            int node = nbase + wave * 32 + rti * 16 + rq * 4 + r;
            if (node < N_NODES) {
                float dv = dinv[node];
#pragma unroll
                for (int ct = 0; ct < 4; ++ct)
                    out[(size_t)node * 64 + ct * 16 + colb] =
                        (_Float16)(acc[rti][ct][r] * dv);
            }
        }
    }
}

// ---------------------------------------------------------------------------
// CSR gather-aggregation, half-wave edge-split (converged at fabric rate):
//   out[v] = dinv[v]*(sum w*h'[r] + h'[v]) + bias
__global__ __launch_bounds__(256) void k_agg(const _Float16* __restrict__ hin,
                                             const unsigned* __restrict__ ebuf2,
                                             const int2* __restrict__ nrange,
                                             const float* __restrict__ dinv,
                                             const float* __restrict__ bias,
                                             _Float16* __restrict__ hout,
                                             float* __restrict__ bn_shard) {
    __shared__ unsigned sme[AGG_CAP];
    __shared__ float sm[4][64], qm[4][64];
    int b = blockIdx.x, t = threadIdx.x;
    int wave = t >> 6, lane = t & 63;
    int half = lane >> 5, hl = lane & 31;
    const unsigned* hinu = (const unsigned*)hin;   // 2 fp16 per uint
    int vbase0 = b * 32;                           // grid is exactly N_NODES/32
    int ebeg = nrange[vbase0].x;
    int eend = nrange[vbase0 + 31].y;
    int n = eend - ebeg;
    bool fit = (n <= AGG_CAP);
    if (fit) {
        for (int i = t; i < n; i += 256) sme[i] = nt_u(ebuf2 + ebeg + i);
    }
    __syncthreads();

    float s0 = 0.f, q0 = 0.f, s1 = 0.f, q1 = 0.f;
    float bl0 = bias[2 * hl], bl1 = bias[2 * hl + 1];
    int vbase = vbase0 + wave * 8;
    for (int vi = 0; vi < 8; ++vi) {
        int v = vbase + vi;
        int2 be = nrange[v];
        int end = be.y;
        float a0 = 0.f, a1 = 0.f;
        int j = be.x + half;
        if (fit) {
            int jl = j - ebeg;
            for (; j + 16 <= end; j += 16, jl += 16) {
                float fw[8];
                unsigned hv[8];
#pragma unroll
                for (int u = 0; u < 8; ++u) {
                    unsigned e = sme[jl + 2 * u];
                    fw[u] = unpack_w(e);
                    hv[u] = hinu[((size_t)(e >> 15) << 5) + hl];
                }
#pragma unroll
                for (int u = 0; u < 8; ++u) {
                    a0 = fmaf(fw[u], f16lo(hv[u]), a0);
                    a1 = fmaf(fw[u], f16hi(hv[u]), a1);
                }
            }
            for (; j < end; j += 2, jl += 2) {
                unsigned e = sme[jl];
                float fw = unpack_w(e);
                unsigned hv = hinu[((size_t)(e >> 15) << 5) + hl];
                a0 = fmaf(fw, f16lo(hv), a0);
                a1 = fmaf(fw, f16hi(hv), a1);
            }
        } else {
            for (; j + 16 <= end; j += 16) {
                float fw[8];
                unsigned hv[8];
#pragma unroll
                for (int u = 0; u < 8; ++u) {
                    unsigned e = nt_u(ebuf2 + j + 2 * u);
                    fw[u] = unpack_w(e);
                    hv[u] = hinu[((size_t)(e >> 15) << 5) + hl];
                }
#pragma unroll
                for (int u = 0; u < 8; ++u) {
                    a0 = fmaf(fw[u], f16lo(hv[u]), a0);
                    a1 = fmaf(fw[u], f16hi(hv[u]), a1);
                }
            }
            for (; j < end; j += 2) {
                unsigned e = nt_u(ebuf2 + j);
                float fw = unpack_w(e);
                unsigned hv = hinu[((size_t)(e >> 15) << 5) + hl];
                a0 = fmaf(fw, f16lo(hv), a0);
                a1 = fmaf(fw, f16hi(hv), a1);
            }
        }
        a0 += __shfl_xor(a0, 32);
        a1 += __shfl_xor(a1, 32);
        unsigned hv = hinu[((size_t)v << 5) + hl];
        float dv = dinv[v];
        a0 = fmaf(dv, a0 + f16lo(hv), bl0);
        a1 = fmaf(dv, a1 + f16hi(hv), bl1);
        if (half == 0) {
            ((unsigned*)hout)[((size_t)v << 5) + hl] = packh2(a0, a1);
            s0 += a0; q0 += a0 * a0;
            s1 += a1; q1 += a1 * a1;
        }
    }
    if (half == 0) {
        sm[wave][2 * hl] = s0; sm[wave][2 * hl + 1] = s1;
        qm[wave][2 * hl] = q0; qm[wave][2 * hl + 1] = q1;
    }
    __syncthreads();
    if (wave == 0) {
        float ts = sm[0][lane] + sm[1][lane] + sm[2][lane] + sm[3][lane];
        float tq = qm[0][lane] + qm[1][lane] + qm[2][lane] + qm[3][lane];
        float* shard = bn_shard + (blockIdx.x & (NSHARD - 1)) * 128;
        atomicAdd(&shard[lane], ts);
        atomicAdd(&shard[64 + lane], tq);
    }
}

// ---------------------------------------------------------------------------
// pool: 782 blocks x 128 rows, sharded accumulators; BN2 scale/shift computed
// INLINE from the layer-2 BN shard buffer (replaces the second k_bn_final).
__global__ __launch_bounds__(256) void k_pool(const _Float16* __restrict__ a2,
                                              const float* __restrict__ bnshard,
                                              const float* __restrict__ gamma,
                                              const float* __restrict__ beta,
                                              const int* __restrict__ batch,
                                              float* __restrict__ pooled_sh,
                                              float* __restrict__ pcnt_sh) {
    int b = blockIdx.x, t = threadIdx.x;
    int c = t & 63;
    int rg = t >> 6;
    int base = b * BUCK_SZ;
    float s = 0.f, q = 0.f;
#pragma unroll
    for (int i = 0; i < NSHARD; ++i) {
        s += bnshard[i * 128 + c];
        q += bnshard[i * 128 + 64 + c];
    }
    float mean = s * (1.0f / N_NODES);
    float var = q * (1.0f / N_NODES) - mean * mean;
    float sc = gamma[c] * rsqrtf(var + BN_EPS);
    float sh = beta[c] - mean * sc;
    float* pool_s = pooled_sh + (size_t)(b & (NSHARD - 1)) * (N_GRAPHS * 64);
    float* pcnt_s = pcnt_sh + (size_t)(b & (NSHARD - 1)) * N_GRAPHS;
    int gcur = -1;
    float acc = 0.f, cacc = 0.f;
    for (int i = rg; i < BUCK_SZ; i += 4) {
        int v = base + i;
        if (v >= N_NODES) break;
        int g = batch[v];
        if (g != gcur) {
            if (gcur >= 0) {
                atomicAdd(&pool_s[gcur * 64 + c], acc);
                if (c == 0) atomicAdd(&pcnt_s[gcur], cacc);
            }
            gcur = g;
            acc = 0.f;
            cacc = 0.f;
        }
        float h = fmaxf(sc * (float)a2[(size_t)v * 64 + c] + sh, 0.f);
        acc += h;
        cacc += 1.f;
    }
    if (gcur >= 0) {
        atomicAdd(&pool_s[gcur * 64 + c], acc);
        if (c == 0) atomicAdd(&pcnt_s[gcur], cacc);
    }
}

__global__ void k_out(const float* __restrict__ pooled_sh,
                      const float* __restrict__ pcnt_sh,
                      const float* __restrict__ Wout, const float* __restrict__ bout,
                      float* __restrict__ out) {
    int g = threadIdx.x;
    if (g < N_GRAPHS) {
        float cnt = 0.f;
        for (int s = 0; s < NSHARD; ++s) cnt += pcnt_sh[s * N_GRAPHS + g];
        cnt = fmaxf(cnt, 1.0f);
        float sum = 0.f;
        for (int c = 0; c < 64; ++c) {
            float p = 0.f;
            for (int s = 0; s < NSHARD; ++s)
                p += pooled_sh[(size_t)s * N_GRAPHS * 64 + g * 64 + c];
            sum += p * Wout[c];
        }
        out[g] = sum / cnt + bout[0];
    }
}

// ---------------------------------------------------------------------------
extern "C" void kernel_launch(void* const* d_in, const int* in_sizes, int n_in,
                              void* d_out, int out_size, void* d_ws, size_t ws_size,
                              hipStream_t stream) {
    const float* x    = (const float*)d_in[0];
    const int*   ei   = (const int*)d_in[1];
    const float* ew   = (const float*)d_in[2];
    const int*   batch= (const int*)d_in[3];
    const float* W1   = (const float*)d_in[4];
    const float* b1   = (const float*)d_in[5];
    const float* W2   = (const float*)d_in[6];
    const float* b2   = (const float*)d_in[7];
    const float* g1   = (const float*)d_in[8];
    const float* be1  = (const float*)d_in[9];
    const float* g2   = (const float*)d_in[10];
    const float* be2  = (const float*)d_in[11];
    const float* Wout = (const float*)d_in[12];
    const float* bout = (const float*)d_in[13];
    float* out = (float*)d_out;

    char* w = (char*)d_ws;
    size_t o = 0;
    auto alloc = [&](size_t bytes) -> void* {
        void* p = w + o;
        o = (o + bytes + 255) & ~(size_t)255;
        return p;
    };
    int*   cur      = (int*)alloc(NCNT * 4);
    int2*  nrange   = (int2*)alloc((size_t)N_NODES * 8);
    float* dinv     = (float*)alloc(N_NODES * 4);
    float* bnshardA = (float*)alloc(NSHARD * 128 * 4);
    float* bnshardB = (float*)alloc(NSHARD * 128 * 4);
    float* pooled   = (float*)alloc(NSHARD * N_GRAPHS * 64 * 4);
    float* pcnt     = (float*)alloc(NSHARD * N_GRAPHS * 4);
    unsigned* ebuf2 = (unsigned*)alloc((size_t)NBUCK * BCAP * 4);  // 14.4 MB
    // 38.4 MB region double-use: ebuf (slotted binning scratch, dead after
    // k_sortnorm), then two fp16 node buffers HA/HB (12.8 MB each).
    uint2* ebuf     = (uint2*)alloc((size_t)NCNT * SLOT_CAP * 8);  // 38.4 MB
    _Float16* bufHA = (_Float16*)ebuf;
    _Float16* bufHB = bufHA + (size_t)N_NODES * 64;
    if (o > ws_size) return;

    k_init<<<256, 256, 0, stream>>>(cur, bnshardA, bnshardB, pooled, pcnt);
    k_bin<<<BIN_BLOCKS, 512, 0, stream>>>(ei, ew, cur, ebuf);
    k_sortnorm<<<NBUCK, 512, 0, stream>>>(ebuf, cur, dinv, ebuf2, nrange);

    // layer 1: x (f32) -> h1' = dinv*(x@W1) (fp16, MFMA) -> a1 + BN1 shards
    k_gemm<128, false><<<(N_NODES + 127) / 128, 256, 0, stream>>>(x, W1, nullptr, nullptr, nullptr, dinv, bufHA);
    k_agg<<<N_NODES / 32, 256, 0, stream>>>(bufHA, ebuf2, nrange, dinv, b1, bufHB, bnshardA);

    // layer 2: a1 (fp16, inline-BN1+ReLU) -> h2' (fp16, MFMA) -> a2 + BN2 shards
    k_gemm<64, true><<<(N_NODES + 127) / 128, 256, 0, stream>>>(bufHB, W2, bnshardA, g1, be1, dinv, bufHA);
    k_agg<<<N_NODES / 32, 256, 0, stream>>>(bufHA, ebuf2, nrange, dinv, b2, bufHB, bnshardB);

    // pool (inline-BN2+ReLU, sharded accumulators) + output
    k_pool<<<NBUCK, 256, 0, stream>>>(bufHB, bnshardB, g2, be2, batch, pooled, pcnt);
    k_out<<<1, 64, 0, stream>>>(pooled, pcnt, Wout, bout, out);
}